// Round 7
// baseline (964.299 us; speedup 1.0000x reference)
//
#include <hip/hip_runtime.h>

// Problem constants (match reference setup_inputs)
constexpr int NN = 50000;     // nodes
constexpr int NE = 1600000;   // edges
constexpr int H  = 128;       // feature dim (F_IN == H)
constexpr int LH = 256;       // lstm hidden
constexpr int OD = 32;        // output dim
constexpr int NG = 64;        // graphs

// Bucketed CSR build: bucket = dst >> 8 (256 nodes per bucket)
constexpr int NBKT  = (NN + 255) / 256;           // 196
constexpr int PARTE = 4096;                       // edges per k_part block
constexpr int NPARTB = (NE + PARTE - 1) / PARTE;  // 391
static_assert(NBKT <= 256, "single-block scan assumes NBKT <= 256");

// Feature chunking: 8 chunks x 16 floats. t'/agg stored as tc[(c*NN+n)*16+fl].
// Gather blocks with chunk==blockIdx&7 land on one XCD (round-robin heuristic)
// -> per-XCD L2 working set = NN*64B = 3.2 MB < 4 MB.
constexpr int NCH = 8;
constexpr int CHW = 16;

// ---------------------------------------------------------------- pass A: bucket histogram (LDS-aggregated)
__global__ __launch_bounds__(256) void k_bhist(const int* __restrict__ col,
                                               int* __restrict__ bktCnt) {
    __shared__ int h[NBKT];
    int t = threadIdx.x;
    if (t < NBKT) h[t] = 0;
    __syncthreads();
    for (int i = blockIdx.x * 256 + t; i < NE; i += gridDim.x * 256)
        atomicAdd(&h[col[i] >> 8], 1);
    __syncthreads();
    if (t < NBKT && h[t] > 0) atomicAdd(&bktCnt[t], h[t]);
}

// ---------------------------------------------------------------- pass B: scan bucket counts
__global__ __launch_bounds__(256) void k_bscan(const int* __restrict__ bktCnt,
                                               int* __restrict__ bktBase,
                                               int* __restrict__ bktCursor) {
    __shared__ int sh[256];
    int t = threadIdx.x;
    int v = (t < NBKT) ? bktCnt[t] : 0;
    sh[t] = v;
    __syncthreads();
    for (int off = 1; off < 256; off <<= 1) {
        int add = (t >= off) ? sh[t - off] : 0;
        __syncthreads();
        sh[t] += add;
        __syncthreads();
    }
    if (t < NBKT) {
        int excl = sh[t] - v;
        bktBase[t] = excl;
        bktCursor[t] = excl;
    }
    if (t == NBKT - 1) bktBase[NBKT] = sh[t];
}

// ---------------------------------------------------------------- pass C: partition edges into bucket-ordered (src,dst)
__global__ __launch_bounds__(256) void k_part(const int* __restrict__ ei,
                                              int* __restrict__ bktCursor,
                                              int2* __restrict__ part) {
    __shared__ int lcur[NBKT];
    __shared__ int lbase[NBKT];
    const int t = threadIdx.x;
    const int base = blockIdx.x * PARTE;
    int sr[16], ds[16], bk[16];

    if (t < NBKT) lcur[t] = 0;
    __syncthreads();
#pragma unroll
    for (int j = 0; j < 16; ++j) {
        int e = base + j * 256 + t;
        if (e < NE) {
            sr[j] = ei[e];
            ds[j] = ei[NE + e];
            bk[j] = ds[j] >> 8;
            atomicAdd(&lcur[bk[j]], 1);
        }
    }
    __syncthreads();
    if (t < NBKT) {
        int c = lcur[t];
        lbase[t] = (c > 0) ? atomicAdd(&bktCursor[t], c) : 0;
        lcur[t] = 0;
    }
    __syncthreads();
#pragma unroll
    for (int j = 0; j < 16; ++j) {
        int e = base + j * 256 + t;
        if (e < NE) {
            int r = atomicAdd(&lcur[bk[j]], 1);
            part[lbase[bk[j]] + r] = make_int2(sr[j], ds[j]);
        }
    }
}

// ---------------------------------------------------------------- pass D: per-bucket CSR finalize (all atomics in LDS)
__global__ __launch_bounds__(256) void k_bfill(const int* __restrict__ bktBase,
                                               const int2* __restrict__ part,
                                               int* __restrict__ rp,
                                               int* __restrict__ cnt,
                                               float* __restrict__ dinv,
                                               int* __restrict__ srcs) {
    __shared__ int h[256];
    __shared__ int sc[256];
    __shared__ int cur[256];
    const int b = blockIdx.x, t = threadIdx.x;
    const int lo = bktBase[b], hi = bktBase[b + 1];

    h[t] = 0;
    __syncthreads();
    for (int i = lo + t; i < hi; i += 256)
        atomicAdd(&h[part[i].y & 255], 1);
    __syncthreads();
    int v = h[t];
    sc[t] = v;
    __syncthreads();
    for (int off = 1; off < 256; off <<= 1) {
        int add = (t >= off) ? sc[t - off] : 0;
        __syncthreads();
        sc[t] += add;
        __syncthreads();
    }
    int excl = sc[t] - v;
    cur[t] = lo + excl;
    int node = b * 256 + t;
    if (node < NN) {
        rp[node] = lo + excl;
        cnt[node] = v;
        dinv[node] = rsqrtf((float)v + 1.0f);   // self-loop adds 1
    }
    __syncthreads();
    for (int i = lo + t; i < hi; i += 256) {
        int2 e = part[i];
        int pos = atomicAdd(&cur[e.y & 255], 1);
        srcs[pos] = e.x;
    }
}

// ---------------------------------------------------------------- GEMM t' = (relu?)(h) @ W * dinv[row]
// Output chunk-major. Input row-major (layer 0: x) or chunk-major (agg).
template <bool RELU, bool CHIN>
__global__ __launch_bounds__(256) void k_gemm(const float* __restrict__ h,
                                              const float* __restrict__ W,
                                              const float* __restrict__ dinv,
                                              float* __restrict__ t) {
    const int tid  = threadIdx.x;
    const int lane = tid & 63;
    const int wave = tid >> 6;
    const int colg = lane & 31;                 // 0..31 -> cols colg*4..+3
    const int rowg = (wave << 1) | (lane >> 5); // 0..7  -> 8 rows each
    const int rb   = blockIdx.x * 64 + rowg * 8;

    const float4* __restrict__ W4 = reinterpret_cast<const float4*>(W);

    float4 acc[8];
#pragma unroll
    for (int r = 0; r < 8; ++r) acc[r] = make_float4(0.f, 0.f, 0.f, 0.f);

    int rowid[8];
#pragma unroll
    for (int r = 0; r < 8; ++r) {
        int rr   = rb + r;
        rowid[r] = rr < NN ? rr : NN - 1;   // clamp loads, guard stores
    }

    for (int k0 = 0; k0 < H; k0 += 4) {
        float4 wv0 = W4[(k0 + 0) * 32 + colg];
        float4 wv1 = W4[(k0 + 1) * 32 + colg];
        float4 wv2 = W4[(k0 + 2) * 32 + colg];
        float4 wv3 = W4[(k0 + 3) * 32 + colg];
#pragma unroll
        for (int r = 0; r < 8; ++r) {
            float4 hv;
            if (CHIN) {
                // chunk-major: floats k0..k0+3 live in chunk k0>>4 at offset k0&12
                hv = *reinterpret_cast<const float4*>(
                    h + ((size_t)(k0 >> 4) * NN + rowid[r]) * CHW + (k0 & 12));
            } else {
                hv = *reinterpret_cast<const float4*>(h + (size_t)rowid[r] * H + k0);
            }
            if (RELU) {
                hv.x = fmaxf(hv.x, 0.f); hv.y = fmaxf(hv.y, 0.f);
                hv.z = fmaxf(hv.z, 0.f); hv.w = fmaxf(hv.w, 0.f);
            }
            acc[r].x = fmaf(hv.x, wv0.x, fmaf(hv.y, wv1.x, fmaf(hv.z, wv2.x, fmaf(hv.w, wv3.x, acc[r].x))));
            acc[r].y = fmaf(hv.x, wv0.y, fmaf(hv.y, wv1.y, fmaf(hv.z, wv2.y, fmaf(hv.w, wv3.y, acc[r].y))));
            acc[r].z = fmaf(hv.x, wv0.z, fmaf(hv.y, wv1.z, fmaf(hv.z, wv2.z, fmaf(hv.w, wv3.z, acc[r].z))));
            acc[r].w = fmaf(hv.x, wv0.w, fmaf(hv.y, wv1.w, fmaf(hv.z, wv2.w, fmaf(hv.w, wv3.w, acc[r].w))));
        }
    }

#pragma unroll
    for (int r = 0; r < 8; ++r) {
        int rr = rb + r;
        if (rr < NN) {
            float d = dinv[rr];
            acc[r].x *= d; acc[r].y *= d; acc[r].z *= d; acc[r].w *= d;
            // chunk-major store: cols colg*4..+3 -> chunk colg>>2, offset (colg&3)*4
            *reinterpret_cast<float4*>(
                t + ((size_t)(colg >> 2) * NN + rr) * CHW + (colg & 3) * 4) = acc[r];
        }
    }
}

// ---------------------------------------------------------------- gather (chunk-major):
// agg_c[n] = bg_c + dinv[n] * (t_c[n] + sum_e t_c[src[e]])
// Block: chunk = blockIdx&7 (XCD affinity), 16 nodes. Wave: 4 edge-slots x 16 feat lanes.
__global__ __launch_bounds__(256) void k_gather(const int* __restrict__ rp,
                                                const int* __restrict__ cnt,
                                                const int* __restrict__ srcs,
                                                const float* __restrict__ dinv,
                                                const float* __restrict__ bg,
                                                const float* __restrict__ t,
                                                float* __restrict__ agg) {
    const int tid  = threadIdx.x;
    const int wv   = tid >> 6;         // 0..3
    const int lane = tid & 63;
    const int g    = lane >> 4;        // edge slot 0..3
    const int fl   = lane & 15;        // feature within chunk
    const int c    = blockIdx.x & 7;   // chunk (-> XCD via round-robin heuristic)
    const int nb   = blockIdx.x >> 3;  // node group
    const int n0   = nb * 16 + wv * 4;

    const float* __restrict__ tc = t + (size_t)c * NN * CHW;
    const float bgv = bg[c * CHW + fl];

#pragma unroll
    for (int k = 0; k < 4; ++k) {
        const int n = n0 + k;          // wave-uniform; NN divisible by 16 -> always < NN
        const int i0 = rp[n], deg = cnt[n];
        float acc = 0.f;
        for (int i = i0 + g; i < i0 + deg; i += 4)
            acc += tc[(size_t)srcs[i] * CHW + fl];
        acc += __shfl_xor(acc, 16);
        acc += __shfl_xor(acc, 32);
        if (g == 0) {
            float tot = acc + tc[(size_t)n * CHW + fl];   // self-loop term
            agg[((size_t)c * NN + n) * CHW + fl] = fmaf(tot, dinv[n], bgv);
        }
    }
}

// ---------------------------------------------------------------- mean pool (batch sorted -> binary search bounds)
__device__ __forceinline__ int lower_bound_dev(const int* __restrict__ b, int v) {
    int lo = 0, hi = NN;
    while (lo < hi) {
        int m = (lo + hi) >> 1;
        if (b[m] < v) lo = m + 1; else hi = m;
    }
    return lo;
}

__global__ __launch_bounds__(128) void k_pool(const int* __restrict__ batch,
                                              const float* __restrict__ agg,  // chunk-major
                                              float* __restrict__ pooled,
                                              float* __restrict__ gcnt) {
    int g = blockIdx.x >> 3;   // 8 blocks per graph
    int q = blockIdx.x & 7;
    int tid = threadIdx.x;     // feature index f = (tid>>4)*16 + (tid&15) = tid
    int s = lower_bound_dev(batch, g);
    int e = lower_bound_dev(batch, g + 1);
    const float* __restrict__ ac = agg + (size_t)(tid >> 4) * NN * CHW + (tid & 15);
    float sum = 0.f;
    for (int n = s + q; n < e; n += 8)
        sum += fmaxf(ac[(size_t)n * CHW], 0.f);   // ReLU fused
    atomicAdd(&pooled[g * H + tid], sum);
    if (q == 0 && tid == 0) gcnt[g] = (float)(e - s);
}

// ---------------------------------------------------------------- LSTM (single step, h0=c0=0) + output head, fused
__global__ __launch_bounds__(256) void k_lstm(const float* __restrict__ pooled,
                                              const float* __restrict__ gcnt,
                                              const float* __restrict__ W_ih,
                                              const float* __restrict__ b_ih,
                                              const float* __restrict__ b_hh,
                                              const float* __restrict__ W_out,
                                              const float* __restrict__ b_out,
                                              float* __restrict__ out) {
    __shared__ __align__(16) float p[H];
    __shared__ __align__(16) float hn[LH];
    int g = blockIdx.x, t = threadIdx.x;
    if (t < H) p[t] = pooled[g * H + t] / fmaxf(gcnt[g], 1.f);
    __syncthreads();

    // gate rows (torch order i,f,g,o): f unused (c0=0)
    float si = b_ih[t] + b_hh[t];
    float sg = b_ih[2 * LH + t] + b_hh[2 * LH + t];
    float so = b_ih[3 * LH + t] + b_hh[3 * LH + t];
    const float* wi = W_ih + (size_t)t * H;
    const float* wg = W_ih + (size_t)(2 * LH + t) * H;
    const float* wo = W_ih + (size_t)(3 * LH + t) * H;
    for (int k = 0; k < H; k += 4) {
        float4 pv = *reinterpret_cast<const float4*>(&p[k]);
        float4 a = *reinterpret_cast<const float4*>(wi + k);
        si += pv.x * a.x + pv.y * a.y + pv.z * a.z + pv.w * a.w;
        float4 b = *reinterpret_cast<const float4*>(wg + k);
        sg += pv.x * b.x + pv.y * b.y + pv.z * b.z + pv.w * b.w;
        float4 c = *reinterpret_cast<const float4*>(wo + k);
        so += pv.x * c.x + pv.y * c.y + pv.z * c.z + pv.w * c.w;
    }
    float ig = 1.f / (1.f + expf(-si));
    float cc = ig * tanhf(sg);
    float og = 1.f / (1.f + expf(-so));
    hn[t] = og * tanhf(cc);
    __syncthreads();

    if (t < OD) {
        float acc = b_out[t];
        const float* wr = W_out + (size_t)t * LH;
        for (int k = 0; k < LH; k += 4) {
            float4 hv = *reinterpret_cast<const float4*>(&hn[k]);
            float4 wv = *reinterpret_cast<const float4*>(wr + k);
            acc += hv.x * wv.x + hv.y * wv.y + hv.z * wv.z + hv.w * wv.w;
        }
        out[g * OD + t] = acc;
    }
}

// ----------------------------------------------------------------
extern "C" void kernel_launch(void* const* d_in, const int* in_sizes, int n_in,
                              void* d_out, int out_size, void* d_ws, size_t ws_size,
                              hipStream_t stream) {
    const float* x     = (const float*)d_in[0];
    const int*   ei    = (const int*)d_in[1];   // [2][NE]: rows then cols
    const int*   batch = (const int*)d_in[2];
    const float* Wg    = (const float*)d_in[3]; // [3][128][128]
    const float* bg    = (const float*)d_in[4]; // [3][128]
    const float* W_ih  = (const float*)d_in[5]; // [1024][128]
    const float* b_ih  = (const float*)d_in[7];
    const float* b_hh  = (const float*)d_in[8];
    const float* W_out = (const float*)d_in[9]; // [32][256]
    const float* b_out = (const float*)d_in[10];
    float* out = (float*)d_out;

    // workspace layout (~71 MB)
    float* ws        = (float*)d_ws;
    float* buf0      = ws;                           // NN*H  (t', chunk-major)
    float* buf1      = buf0 + (size_t)NN * H;        // NN*H  (agg, chunk-major)
    int2*  part      = (int2*)(buf1 + (size_t)NN * H); // NE int2 (8B-aligned)
    float* dinv      = (float*)(part + NE);          // NN
    float* pooled    = dinv + NN;                    // NG*H
    float* gcnt      = pooled + NG * H;              // NG
    int*   cnt       = (int*)(gcnt + NG);            // NN
    int*   rp        = cnt + NN;                     // NN
    int*   srcs      = rp + NN;                      // NE
    int*   bktCnt    = srcs + NE;                    // NBKT
    int*   bktBase   = bktCnt + NBKT;                // NBKT+1
    int*   bktCursor = bktBase + NBKT + 1;           // NBKT

    hipMemsetAsync(bktCnt, 0, NBKT * sizeof(int), stream);
    hipMemsetAsync(pooled, 0, (NG * H + NG) * sizeof(float), stream);

    // CSR build (by destination) — bucketed counting sort
    k_bhist<<<256, 256, 0, stream>>>(ei + NE, bktCnt);
    k_bscan<<<1, 256, 0, stream>>>(bktCnt, bktBase, bktCursor);
    k_part <<<NPARTB, 256, 0, stream>>>(ei, bktCursor, part);
    k_bfill<<<NBKT, 256, 0, stream>>>(bktBase, part, rp, cnt, dinv, srcs);

    const int gemmBlocks = (NN + 63) / 64;
    const int gathBlocks = (NN / 16) * NCH;   // 50000/16 * 8 = 25000

    // layer 0: x (row-major) -> buf0 -> buf1
    k_gemm<false, false><<<gemmBlocks, 256, 0, stream>>>(x, Wg, dinv, buf0);
    k_gather<<<gathBlocks, 256, 0, stream>>>(rp, cnt, srcs, dinv, bg, buf0, buf1);
    // layer 1: relu(buf1) -> buf0 -> buf1
    k_gemm<true, true><<<gemmBlocks, 256, 0, stream>>>(buf1, Wg + H * H, dinv, buf0);
    k_gather<<<gathBlocks, 256, 0, stream>>>(rp, cnt, srcs, dinv, bg + H, buf0, buf1);
    // layer 2: relu(buf1) -> buf0 -> buf1
    k_gemm<true, true><<<gemmBlocks, 256, 0, stream>>>(buf1, Wg + 2 * H * H, dinv, buf0);
    k_gather<<<gathBlocks, 256, 0, stream>>>(rp, cnt, srcs, dinv, bg + 2 * H, buf0, buf1);

    k_pool<<<NG * 8, 128, 0, stream>>>(batch, buf1, pooled, gcnt);
    k_lstm<<<NG, 256, 0, stream>>>(pooled, gcnt, W_ih, b_ih, b_hh, W_out, b_out, out);
}

// Round 8
// 616.015 us; speedup vs baseline: 1.5654x; 1.5654x over previous
//
#include <hip/hip_runtime.h>

// Problem constants (match reference setup_inputs)
constexpr int NN = 50000;     // nodes
constexpr int NE = 1600000;   // edges
constexpr int H  = 128;       // feature dim (F_IN == H)
constexpr int LH = 256;       // lstm hidden
constexpr int OD = 32;        // output dim
constexpr int NG = 64;        // graphs

// Bucketed CSR build: bucket = dst >> 8 (256 nodes per bucket)
constexpr int NBKT  = (NN + 255) / 256;           // 196
constexpr int PARTE = 4096;                       // edges per k_part block
constexpr int NPARTB = (NE + PARTE - 1) / PARTE;  // 391
static_assert(NBKT <= 256, "single-block scan assumes NBKT <= 256");

// Feature chunking: 8 chunks x 16 floats. t'/agg stored as tc[(c*NN+n)*16+fl].
// Gather blocks with chunk==blockIdx&7 land on one XCD (round-robin heuristic)
// -> per-XCD L2 working set = NN*64B = 3.2 MB < 4 MB. (R7 PMC: FETCH 360->50MB.)
constexpr int NCH = 8;
constexpr int CHW = 16;

// ---------------------------------------------------------------- pass A: bucket histogram (LDS-aggregated)
__global__ __launch_bounds__(256) void k_bhist(const int* __restrict__ col,
                                               int* __restrict__ bktCnt) {
    __shared__ int h[NBKT];
    int t = threadIdx.x;
    if (t < NBKT) h[t] = 0;
    __syncthreads();
    for (int i = blockIdx.x * 256 + t; i < NE; i += gridDim.x * 256)
        atomicAdd(&h[col[i] >> 8], 1);
    __syncthreads();
    if (t < NBKT && h[t] > 0) atomicAdd(&bktCnt[t], h[t]);
}

// ---------------------------------------------------------------- pass B: scan bucket counts
__global__ __launch_bounds__(256) void k_bscan(const int* __restrict__ bktCnt,
                                               int* __restrict__ bktBase,
                                               int* __restrict__ bktCursor) {
    __shared__ int sh[256];
    int t = threadIdx.x;
    int v = (t < NBKT) ? bktCnt[t] : 0;
    sh[t] = v;
    __syncthreads();
    for (int off = 1; off < 256; off <<= 1) {
        int add = (t >= off) ? sh[t - off] : 0;
        __syncthreads();
        sh[t] += add;
        __syncthreads();
    }
    if (t < NBKT) {
        int excl = sh[t] - v;
        bktBase[t] = excl;
        bktCursor[t] = excl;
    }
    if (t == NBKT - 1) bktBase[NBKT] = sh[t];
}

// ---------------------------------------------------------------- pass C: partition edges into bucket-ordered (src,dst)
__global__ __launch_bounds__(256) void k_part(const int* __restrict__ ei,
                                              int* __restrict__ bktCursor,
                                              int2* __restrict__ part) {
    __shared__ int lcur[NBKT];
    __shared__ int lbase[NBKT];
    const int t = threadIdx.x;
    const int base = blockIdx.x * PARTE;
    int sr[16], ds[16], bk[16];

    if (t < NBKT) lcur[t] = 0;
    __syncthreads();
#pragma unroll
    for (int j = 0; j < 16; ++j) {
        int e = base + j * 256 + t;
        if (e < NE) {
            sr[j] = ei[e];
            ds[j] = ei[NE + e];
            bk[j] = ds[j] >> 8;
            atomicAdd(&lcur[bk[j]], 1);
        }
    }
    __syncthreads();
    if (t < NBKT) {
        int c = lcur[t];
        lbase[t] = (c > 0) ? atomicAdd(&bktCursor[t], c) : 0;
        lcur[t] = 0;
    }
    __syncthreads();
#pragma unroll
    for (int j = 0; j < 16; ++j) {
        int e = base + j * 256 + t;
        if (e < NE) {
            int r = atomicAdd(&lcur[bk[j]], 1);
            part[lbase[bk[j]] + r] = make_int2(sr[j], ds[j]);
        }
    }
}

// ---------------------------------------------------------------- pass D: per-bucket CSR finalize (all atomics in LDS)
__global__ __launch_bounds__(256) void k_bfill(const int* __restrict__ bktBase,
                                               const int2* __restrict__ part,
                                               int* __restrict__ rp,
                                               int* __restrict__ cnt,
                                               float* __restrict__ dinv,
                                               int* __restrict__ srcs) {
    __shared__ int h[256];
    __shared__ int sc[256];
    __shared__ int cur[256];
    const int b = blockIdx.x, t = threadIdx.x;
    const int lo = bktBase[b], hi = bktBase[b + 1];

    h[t] = 0;
    __syncthreads();
    for (int i = lo + t; i < hi; i += 256)
        atomicAdd(&h[part[i].y & 255], 1);
    __syncthreads();
    int v = h[t];
    sc[t] = v;
    __syncthreads();
    for (int off = 1; off < 256; off <<= 1) {
        int add = (t >= off) ? sc[t - off] : 0;
        __syncthreads();
        sc[t] += add;
        __syncthreads();
    }
    int excl = sc[t] - v;
    cur[t] = lo + excl;
    int node = b * 256 + t;
    if (node < NN) {
        rp[node] = lo + excl;
        cnt[node] = v;
        dinv[node] = rsqrtf((float)v + 1.0f);   // self-loop adds 1
    }
    __syncthreads();
    for (int i = lo + t; i < hi; i += 256) {
        int2 e = part[i];
        int pos = atomicAdd(&cur[e.y & 255], 1);
        srcs[pos] = e.x;
    }
}

// ---------------------------------------------------------------- GEMM t' = (relu?)(h) @ W * dinv[row]
// Output chunk-major. Input row-major (layer 0: x) or chunk-major (agg).
template <bool RELU, bool CHIN>
__global__ __launch_bounds__(256) void k_gemm(const float* __restrict__ h,
                                              const float* __restrict__ W,
                                              const float* __restrict__ dinv,
                                              float* __restrict__ t) {
    const int tid  = threadIdx.x;
    const int lane = tid & 63;
    const int wave = tid >> 6;
    const int colg = lane & 31;                 // 0..31 -> cols colg*4..+3
    const int rowg = (wave << 1) | (lane >> 5); // 0..7  -> 8 rows each
    const int rb   = blockIdx.x * 64 + rowg * 8;

    const float4* __restrict__ W4 = reinterpret_cast<const float4*>(W);

    float4 acc[8];
#pragma unroll
    for (int r = 0; r < 8; ++r) acc[r] = make_float4(0.f, 0.f, 0.f, 0.f);

    int rowid[8];
#pragma unroll
    for (int r = 0; r < 8; ++r) {
        int rr   = rb + r;
        rowid[r] = rr < NN ? rr : NN - 1;   // clamp loads, guard stores
    }

    for (int k0 = 0; k0 < H; k0 += 4) {
        float4 wv0 = W4[(k0 + 0) * 32 + colg];
        float4 wv1 = W4[(k0 + 1) * 32 + colg];
        float4 wv2 = W4[(k0 + 2) * 32 + colg];
        float4 wv3 = W4[(k0 + 3) * 32 + colg];
#pragma unroll
        for (int r = 0; r < 8; ++r) {
            float4 hv;
            if (CHIN) {
                // chunk-major: floats k0..k0+3 live in chunk k0>>4 at offset k0&12
                hv = *reinterpret_cast<const float4*>(
                    h + ((size_t)(k0 >> 4) * NN + rowid[r]) * CHW + (k0 & 12));
            } else {
                hv = *reinterpret_cast<const float4*>(h + (size_t)rowid[r] * H + k0);
            }
            if (RELU) {
                hv.x = fmaxf(hv.x, 0.f); hv.y = fmaxf(hv.y, 0.f);
                hv.z = fmaxf(hv.z, 0.f); hv.w = fmaxf(hv.w, 0.f);
            }
            acc[r].x = fmaf(hv.x, wv0.x, fmaf(hv.y, wv1.x, fmaf(hv.z, wv2.x, fmaf(hv.w, wv3.x, acc[r].x))));
            acc[r].y = fmaf(hv.x, wv0.y, fmaf(hv.y, wv1.y, fmaf(hv.z, wv2.y, fmaf(hv.w, wv3.y, acc[r].y))));
            acc[r].z = fmaf(hv.x, wv0.z, fmaf(hv.y, wv1.z, fmaf(hv.z, wv2.z, fmaf(hv.w, wv3.z, acc[r].z))));
            acc[r].w = fmaf(hv.x, wv0.w, fmaf(hv.y, wv1.w, fmaf(hv.z, wv2.w, fmaf(hv.w, wv3.w, acc[r].w))));
        }
    }

#pragma unroll
    for (int r = 0; r < 8; ++r) {
        int rr = rb + r;
        if (rr < NN) {
            float d = dinv[rr];
            acc[r].x *= d; acc[r].y *= d; acc[r].z *= d; acc[r].w *= d;
            // chunk-major store: cols colg*4..+3 -> chunk colg>>2, offset (colg&3)*4
            *reinterpret_cast<float4*>(
                t + ((size_t)(colg >> 2) * NN + rr) * CHW + (colg & 3) * 4) = acc[r];
        }
    }
}

// ---------------------------------------------------------------- gather (chunk-major, float4/lane):
// agg_c[n] = bg_c + dinv[n] * (t_c[n] + sum_e t_c[src[e]])
// Wave: 16 edge-slots x 4 lanes; each lane reads one float4 of the 64B chunk
// row -> 1 KB / wave-instr, all L2-resident. Butterfly-reduce across slots.
__global__ __launch_bounds__(256) void k_gather(const int* __restrict__ rp,
                                                const int* __restrict__ cnt,
                                                const int* __restrict__ srcs,
                                                const float* __restrict__ dinv,
                                                const float* __restrict__ bg,
                                                const float* __restrict__ t,
                                                float* __restrict__ agg) {
    const int tid  = threadIdx.x;
    const int wv   = tid >> 6;         // 0..3
    const int lane = tid & 63;
    const int slot = lane >> 2;        // 0..15 edge slot
    const int l4   = lane & 3;         // float4 index within 64B row
    const int c    = blockIdx.x & 7;   // chunk (-> XCD via round-robin heuristic)
    const int nb   = blockIdx.x >> 3;  // node group
    const int n0   = nb * 8 + wv * 2;  // 2 nodes per wave

    const float4* __restrict__ tc4 =
        reinterpret_cast<const float4*>(t + (size_t)c * NN * CHW);
    const float4 bgv = reinterpret_cast<const float4*>(bg + c * CHW)[l4];

#pragma unroll
    for (int k = 0; k < 2; ++k) {
        const int n = n0 + k;          // wave-uniform; NN % 8 == 0 -> always < NN
        const int i0 = rp[n];
        const int end = i0 + cnt[n];
        float4 acc = make_float4(0.f, 0.f, 0.f, 0.f);

        int i = i0 + slot;
        // unroll-2: both srcs loads issue before the dependent row loads (2-way MLP)
        for (; i + 16 < end; i += 32) {
            int sA = srcs[i];
            int sB = srcs[i + 16];
            float4 vA = tc4[(size_t)sA * 4 + l4];
            float4 vB = tc4[(size_t)sB * 4 + l4];
            acc.x += vA.x + vB.x; acc.y += vA.y + vB.y;
            acc.z += vA.z + vB.z; acc.w += vA.w + vB.w;
        }
        for (; i < end; i += 16) {
            int s = srcs[i];
            float4 v = tc4[(size_t)s * 4 + l4];
            acc.x += v.x; acc.y += v.y; acc.z += v.z; acc.w += v.w;
        }

        // butterfly over slot bits (lane bits 2..5)
#pragma unroll
        for (int m = 4; m <= 32; m <<= 1) {
            acc.x += __shfl_xor(acc.x, m);
            acc.y += __shfl_xor(acc.y, m);
            acc.z += __shfl_xor(acc.z, m);
            acc.w += __shfl_xor(acc.w, m);
        }

        if (slot == 0) {
            float4 sv = tc4[(size_t)n * 4 + l4];   // self-loop term
            float d = dinv[n];
            float4 o;
            o.x = fmaf(acc.x + sv.x, d, bgv.x);
            o.y = fmaf(acc.y + sv.y, d, bgv.y);
            o.z = fmaf(acc.z + sv.z, d, bgv.z);
            o.w = fmaf(acc.w + sv.w, d, bgv.w);
            reinterpret_cast<float4*>(agg)[((size_t)c * NN + n) * 4 + l4] = o;
        }
    }
}

// ---------------------------------------------------------------- mean pool (batch sorted -> binary search bounds)
__device__ __forceinline__ int lower_bound_dev(const int* __restrict__ b, int v) {
    int lo = 0, hi = NN;
    while (lo < hi) {
        int m = (lo + hi) >> 1;
        if (b[m] < v) lo = m + 1; else hi = m;
    }
    return lo;
}

__global__ __launch_bounds__(128) void k_pool(const int* __restrict__ batch,
                                              const float* __restrict__ agg,  // chunk-major
                                              float* __restrict__ pooled,
                                              float* __restrict__ gcnt) {
    int g = blockIdx.x >> 3;   // 8 blocks per graph
    int q = blockIdx.x & 7;
    int tid = threadIdx.x;     // feature index f = (tid>>4)*16 + (tid&15) = tid
    int s = lower_bound_dev(batch, g);
    int e = lower_bound_dev(batch, g + 1);
    const float* __restrict__ ac = agg + (size_t)(tid >> 4) * NN * CHW + (tid & 15);
    float sum = 0.f;
    for (int n = s + q; n < e; n += 8)
        sum += fmaxf(ac[(size_t)n * CHW], 0.f);   // ReLU fused
    atomicAdd(&pooled[g * H + tid], sum);
    if (q == 0 && tid == 0) gcnt[g] = (float)(e - s);
}

// ---------------------------------------------------------------- LSTM (single step, h0=c0=0) + output head, fused
__global__ __launch_bounds__(256) void k_lstm(const float* __restrict__ pooled,
                                              const float* __restrict__ gcnt,
                                              const float* __restrict__ W_ih,
                                              const float* __restrict__ b_ih,
                                              const float* __restrict__ b_hh,
                                              const float* __restrict__ W_out,
                                              const float* __restrict__ b_out,
                                              float* __restrict__ out) {
    __shared__ __align__(16) float p[H];
    __shared__ __align__(16) float hn[LH];
    int g = blockIdx.x, t = threadIdx.x;
    if (t < H) p[t] = pooled[g * H + t] / fmaxf(gcnt[g], 1.f);
    __syncthreads();

    // gate rows (torch order i,f,g,o): f unused (c0=0)
    float si = b_ih[t] + b_hh[t];
    float sg = b_ih[2 * LH + t] + b_hh[2 * LH + t];
    float so = b_ih[3 * LH + t] + b_hh[3 * LH + t];
    const float* wi = W_ih + (size_t)t * H;
    const float* wg = W_ih + (size_t)(2 * LH + t) * H;
    const float* wo = W_ih + (size_t)(3 * LH + t) * H;
    for (int k = 0; k < H; k += 4) {
        float4 pv = *reinterpret_cast<const float4*>(&p[k]);
        float4 a = *reinterpret_cast<const float4*>(wi + k);
        si += pv.x * a.x + pv.y * a.y + pv.z * a.z + pv.w * a.w;
        float4 b = *reinterpret_cast<const float4*>(wg + k);
        sg += pv.x * b.x + pv.y * b.y + pv.z * b.z + pv.w * b.w;
        float4 c = *reinterpret_cast<const float4*>(wo + k);
        so += pv.x * c.x + pv.y * c.y + pv.z * c.z + pv.w * c.w;
    }
    float ig = 1.f / (1.f + expf(-si));
    float cc = ig * tanhf(sg);
    float og = 1.f / (1.f + expf(-so));
    hn[t] = og * tanhf(cc);
    __syncthreads();

    if (t < OD) {
        float acc = b_out[t];
        const float* wr = W_out + (size_t)t * LH;
        for (int k = 0; k < LH; k += 4) {
            float4 hv = *reinterpret_cast<const float4*>(&hn[k]);
            float4 wv = *reinterpret_cast<const float4*>(wr + k);
            acc += hv.x * wv.x + hv.y * wv.y + hv.z * wv.z + hv.w * wv.w;
        }
        out[g * OD + t] = acc;
    }
}

// ----------------------------------------------------------------
extern "C" void kernel_launch(void* const* d_in, const int* in_sizes, int n_in,
                              void* d_out, int out_size, void* d_ws, size_t ws_size,
                              hipStream_t stream) {
    const float* x     = (const float*)d_in[0];
    const int*   ei    = (const int*)d_in[1];   // [2][NE]: rows then cols
    const int*   batch = (const int*)d_in[2];
    const float* Wg    = (const float*)d_in[3]; // [3][128][128]
    const float* bg    = (const float*)d_in[4]; // [3][128]
    const float* W_ih  = (const float*)d_in[5]; // [1024][128]
    const float* b_ih  = (const float*)d_in[7];
    const float* b_hh  = (const float*)d_in[8];
    const float* W_out = (const float*)d_in[9]; // [32][256]
    const float* b_out = (const float*)d_in[10];
    float* out = (float*)d_out;

    // workspace layout (~71 MB)
    float* ws        = (float*)d_ws;
    float* buf0      = ws;                           // NN*H  (t', chunk-major)
    float* buf1      = buf0 + (size_t)NN * H;        // NN*H  (agg, chunk-major)
    int2*  part      = (int2*)(buf1 + (size_t)NN * H); // NE int2 (8B-aligned)
    float* dinv      = (float*)(part + NE);          // NN
    float* pooled    = dinv + NN;                    // NG*H
    float* gcnt      = pooled + NG * H;              // NG
    int*   cnt       = (int*)(gcnt + NG);            // NN
    int*   rp        = cnt + NN;                     // NN
    int*   srcs      = rp + NN;                      // NE
    int*   bktCnt    = srcs + NE;                    // NBKT
    int*   bktBase   = bktCnt + NBKT;                // NBKT+1
    int*   bktCursor = bktBase + NBKT + 1;           // NBKT

    hipMemsetAsync(bktCnt, 0, NBKT * sizeof(int), stream);
    hipMemsetAsync(pooled, 0, (NG * H + NG) * sizeof(float), stream);

    // CSR build (by destination) — bucketed counting sort
    k_bhist<<<256, 256, 0, stream>>>(ei + NE, bktCnt);
    k_bscan<<<1, 256, 0, stream>>>(bktCnt, bktBase, bktCursor);
    k_part <<<NPARTB, 256, 0, stream>>>(ei, bktCursor, part);
    k_bfill<<<NBKT, 256, 0, stream>>>(bktBase, part, rp, cnt, dinv, srcs);

    const int gemmBlocks = (NN + 63) / 64;
    const int gathBlocks = (NN / 8) * NCH;   // 50000/8 * 8 = 50000

    // layer 0: x (row-major) -> buf0 -> buf1
    k_gemm<false, false><<<gemmBlocks, 256, 0, stream>>>(x, Wg, dinv, buf0);
    k_gather<<<gathBlocks, 256, 0, stream>>>(rp, cnt, srcs, dinv, bg, buf0, buf1);
    // layer 1: relu(buf1) -> buf0 -> buf1
    k_gemm<true, true><<<gemmBlocks, 256, 0, stream>>>(buf1, Wg + H * H, dinv, buf0);
    k_gather<<<gathBlocks, 256, 0, stream>>>(rp, cnt, srcs, dinv, bg + H, buf0, buf1);
    // layer 2: relu(buf1) -> buf0 -> buf1
    k_gemm<true, true><<<gemmBlocks, 256, 0, stream>>>(buf1, Wg + 2 * H * H, dinv, buf0);
    k_gather<<<gathBlocks, 256, 0, stream>>>(rp, cnt, srcs, dinv, bg + 2 * H, buf0, buf1);

    k_pool<<<NG * 8, 128, 0, stream>>>(batch, buf1, pooled, gcnt);
    k_lstm<<<NG, 256, 0, stream>>>(pooled, gcnt, W_ih, b_ih, b_hh, W_out, b_out, out);
}

// Round 9
// 582.566 us; speedup vs baseline: 1.6553x; 1.0574x over previous
//
#include <hip/hip_runtime.h>

// Problem constants (match reference setup_inputs)
constexpr int NN = 50000;     // nodes
constexpr int NE = 1600000;   // edges
constexpr int H  = 128;       // feature dim (F_IN == H)
constexpr int LH = 256;       // lstm hidden
constexpr int OD = 32;        // output dim
constexpr int NG = 64;        // graphs

// Bucketed CSR build: bucket = dst >> 8 (256 nodes per bucket)
constexpr int NBKT  = (NN + 255) / 256;           // 196
constexpr int PARTE = 4096;                       // edges per k_part block
constexpr int NPARTB = (NE + PARTE - 1) / PARTE;  // 391
static_assert(NBKT <= 256, "single-block scan assumes NBKT <= 256");

// Feature chunking: 8 chunks x 16 floats. t'/agg stored as tc[(c*NN+n)*16+fl].
// Gather blocks with chunk==blockIdx&7 land on one XCD (round-robin heuristic)
// -> per-XCD L2 working set = NN*64B = 3.2 MB < 4 MB. (R7/R8 PMC: FETCH 360->46MB.)
constexpr int NCH = 8;
constexpr int CHW = 16;

// ---------------------------------------------------------------- pass A: bucket histogram (LDS-aggregated)
__global__ __launch_bounds__(256) void k_bhist(const int* __restrict__ col,
                                               int* __restrict__ bktCnt) {
    __shared__ int h[NBKT];
    int t = threadIdx.x;
    if (t < NBKT) h[t] = 0;
    __syncthreads();
    for (int i = blockIdx.x * 256 + t; i < NE; i += gridDim.x * 256)
        atomicAdd(&h[col[i] >> 8], 1);
    __syncthreads();
    if (t < NBKT && h[t] > 0) atomicAdd(&bktCnt[t], h[t]);
}

// ---------------------------------------------------------------- pass B: scan bucket counts
__global__ __launch_bounds__(256) void k_bscan(const int* __restrict__ bktCnt,
                                               int* __restrict__ bktBase,
                                               int* __restrict__ bktCursor) {
    __shared__ int sh[256];
    int t = threadIdx.x;
    int v = (t < NBKT) ? bktCnt[t] : 0;
    sh[t] = v;
    __syncthreads();
    for (int off = 1; off < 256; off <<= 1) {
        int add = (t >= off) ? sh[t - off] : 0;
        __syncthreads();
        sh[t] += add;
        __syncthreads();
    }
    if (t < NBKT) {
        int excl = sh[t] - v;
        bktBase[t] = excl;
        bktCursor[t] = excl;
    }
    if (t == NBKT - 1) bktBase[NBKT] = sh[t];
}

// ---------------------------------------------------------------- pass C: partition edges into bucket-ordered (src,dst)
__global__ __launch_bounds__(256) void k_part(const int* __restrict__ ei,
                                              int* __restrict__ bktCursor,
                                              int2* __restrict__ part) {
    __shared__ int lcur[NBKT];
    __shared__ int lbase[NBKT];
    const int t = threadIdx.x;
    const int base = blockIdx.x * PARTE;
    int sr[16], ds[16], bk[16];

    if (t < NBKT) lcur[t] = 0;
    __syncthreads();
#pragma unroll
    for (int j = 0; j < 16; ++j) {
        int e = base + j * 256 + t;
        if (e < NE) {
            sr[j] = ei[e];
            ds[j] = ei[NE + e];
            bk[j] = ds[j] >> 8;
            atomicAdd(&lcur[bk[j]], 1);
        }
    }
    __syncthreads();
    if (t < NBKT) {
        int c = lcur[t];
        lbase[t] = (c > 0) ? atomicAdd(&bktCursor[t], c) : 0;
        lcur[t] = 0;
    }
    __syncthreads();
#pragma unroll
    for (int j = 0; j < 16; ++j) {
        int e = base + j * 256 + t;
        if (e < NE) {
            int r = atomicAdd(&lcur[bk[j]], 1);
            part[lbase[bk[j]] + r] = make_int2(sr[j], ds[j]);
        }
    }
}

// ---------------------------------------------------------------- pass D: per-bucket CSR finalize (all atomics in LDS)
__global__ __launch_bounds__(256) void k_bfill(const int* __restrict__ bktBase,
                                               const int2* __restrict__ part,
                                               int* __restrict__ rp,
                                               int* __restrict__ cnt,
                                               float* __restrict__ dinv,
                                               int* __restrict__ srcs) {
    __shared__ int h[256];
    __shared__ int sc[256];
    __shared__ int cur[256];
    const int b = blockIdx.x, t = threadIdx.x;
    const int lo = bktBase[b], hi = bktBase[b + 1];

    h[t] = 0;
    __syncthreads();
    for (int i = lo + t; i < hi; i += 256)
        atomicAdd(&h[part[i].y & 255], 1);
    __syncthreads();
    int v = h[t];
    sc[t] = v;
    __syncthreads();
    for (int off = 1; off < 256; off <<= 1) {
        int add = (t >= off) ? sc[t - off] : 0;
        __syncthreads();
        sc[t] += add;
        __syncthreads();
    }
    int excl = sc[t] - v;
    cur[t] = lo + excl;
    int node = b * 256 + t;
    if (node < NN) {
        rp[node] = lo + excl;
        cnt[node] = v;
        dinv[node] = rsqrtf((float)v + 1.0f);   // self-loop adds 1
    }
    __syncthreads();
    for (int i = lo + t; i < hi; i += 256) {
        int2 e = part[i];
        int pos = atomicAdd(&cur[e.y & 255], 1);
        srcs[pos] = e.x;
    }
}

// ---------------------------------------------------------------- GEMM t' = (relu?)(h) @ W * dinv[row]
// Output chunk-major. Input row-major (layer 0: x) or chunk-major (agg).
template <bool RELU, bool CHIN>
__global__ __launch_bounds__(256) void k_gemm(const float* __restrict__ h,
                                              const float* __restrict__ W,
                                              const float* __restrict__ dinv,
                                              float* __restrict__ t) {
    const int tid  = threadIdx.x;
    const int lane = tid & 63;
    const int wave = tid >> 6;
    const int colg = lane & 31;                 // 0..31 -> cols colg*4..+3
    const int rowg = (wave << 1) | (lane >> 5); // 0..7  -> 8 rows each
    const int rb   = blockIdx.x * 64 + rowg * 8;

    const float4* __restrict__ W4 = reinterpret_cast<const float4*>(W);

    float4 acc[8];
#pragma unroll
    for (int r = 0; r < 8; ++r) acc[r] = make_float4(0.f, 0.f, 0.f, 0.f);

    int rowid[8];
#pragma unroll
    for (int r = 0; r < 8; ++r) {
        int rr   = rb + r;
        rowid[r] = rr < NN ? rr : NN - 1;   // clamp loads, guard stores
    }

    for (int k0 = 0; k0 < H; k0 += 4) {
        float4 wv0 = W4[(k0 + 0) * 32 + colg];
        float4 wv1 = W4[(k0 + 1) * 32 + colg];
        float4 wv2 = W4[(k0 + 2) * 32 + colg];
        float4 wv3 = W4[(k0 + 3) * 32 + colg];
#pragma unroll
        for (int r = 0; r < 8; ++r) {
            float4 hv;
            if (CHIN) {
                // chunk-major: floats k0..k0+3 live in chunk k0>>4 at offset k0&12
                hv = *reinterpret_cast<const float4*>(
                    h + ((size_t)(k0 >> 4) * NN + rowid[r]) * CHW + (k0 & 12));
            } else {
                hv = *reinterpret_cast<const float4*>(h + (size_t)rowid[r] * H + k0);
            }
            if (RELU) {
                hv.x = fmaxf(hv.x, 0.f); hv.y = fmaxf(hv.y, 0.f);
                hv.z = fmaxf(hv.z, 0.f); hv.w = fmaxf(hv.w, 0.f);
            }
            acc[r].x = fmaf(hv.x, wv0.x, fmaf(hv.y, wv1.x, fmaf(hv.z, wv2.x, fmaf(hv.w, wv3.x, acc[r].x))));
            acc[r].y = fmaf(hv.x, wv0.y, fmaf(hv.y, wv1.y, fmaf(hv.z, wv2.y, fmaf(hv.w, wv3.y, acc[r].y))));
            acc[r].z = fmaf(hv.x, wv0.z, fmaf(hv.y, wv1.z, fmaf(hv.z, wv2.z, fmaf(hv.w, wv3.z, acc[r].z))));
            acc[r].w = fmaf(hv.x, wv0.w, fmaf(hv.y, wv1.w, fmaf(hv.z, wv2.w, fmaf(hv.w, wv3.w, acc[r].w))));
        }
    }

#pragma unroll
    for (int r = 0; r < 8; ++r) {
        int rr = rb + r;
        if (rr < NN) {
            float d = dinv[rr];
            acc[r].x *= d; acc[r].y *= d; acc[r].z *= d; acc[r].w *= d;
            // chunk-major store: cols colg*4..+3 -> chunk colg>>2, offset (colg&3)*4
            *reinterpret_cast<float4*>(
                t + ((size_t)(colg >> 2) * NN + rr) * CHW + (colg & 3) * 4) = acc[r];
        }
    }
}

// ---------------------------------------------------------------- gather (chunk-major, per-node 4-lane groups):
// agg_c[n] = bg_c + dinv[n] * (t_c[n] + sum_e t_c[src[e]])
// Wave: 16 node-groups x 4 lanes. Each group walks its node's edge list;
// lane l4 accumulates float4 #l4 of the 64B chunk row in a register.
// 1 KB / wave row-load, ZERO cross-lane reduction, all lanes write.
__global__ __launch_bounds__(256) void k_gather(const int* __restrict__ rp,
                                                const int* __restrict__ cnt,
                                                const int* __restrict__ srcs,
                                                const float* __restrict__ dinv,
                                                const float* __restrict__ bg,
                                                const float* __restrict__ t,
                                                float* __restrict__ agg) {
    const int tid  = threadIdx.x;
    const int wv   = tid >> 6;         // 0..3
    const int lane = tid & 63;
    const int slot = lane >> 2;        // node group 0..15
    const int l4   = lane & 3;         // float4 index within 64B row
    const int c    = blockIdx.x & 7;   // chunk (-> XCD via round-robin heuristic)
    const int nb   = blockIdx.x >> 3;  // node block (64 nodes)
    const int n    = nb * 64 + wv * 16 + slot;

    if (n >= NN) return;               // group-uniform

    const float4* __restrict__ tc4 =
        reinterpret_cast<const float4*>(t + (size_t)c * NN * CHW);
    const float4 bgv = reinterpret_cast<const float4*>(bg + c * CHW)[l4];

    const int i0  = rp[n];
    const int end = i0 + cnt[n];
    float4 acc = make_float4(0.f, 0.f, 0.f, 0.f);

    int i = i0;
    // unroll-4: 4 independent srcs loads, then 4 independent row loads (4-way MLP)
    for (; i + 3 < end; i += 4) {
        int s0 = srcs[i], s1 = srcs[i + 1], s2 = srcs[i + 2], s3 = srcs[i + 3];
        float4 v0 = tc4[(size_t)s0 * 4 + l4];
        float4 v1 = tc4[(size_t)s1 * 4 + l4];
        float4 v2 = tc4[(size_t)s2 * 4 + l4];
        float4 v3 = tc4[(size_t)s3 * 4 + l4];
        acc.x += (v0.x + v1.x) + (v2.x + v3.x);
        acc.y += (v0.y + v1.y) + (v2.y + v3.y);
        acc.z += (v0.z + v1.z) + (v2.z + v3.z);
        acc.w += (v0.w + v1.w) + (v2.w + v3.w);
    }
    for (; i < end; ++i) {
        int s = srcs[i];
        float4 v = tc4[(size_t)s * 4 + l4];
        acc.x += v.x; acc.y += v.y; acc.z += v.z; acc.w += v.w;
    }

    float4 sv = tc4[(size_t)n * 4 + l4];   // self-loop term
    float d = dinv[n];
    float4 o;
    o.x = fmaf(acc.x + sv.x, d, bgv.x);
    o.y = fmaf(acc.y + sv.y, d, bgv.y);
    o.z = fmaf(acc.z + sv.z, d, bgv.z);
    o.w = fmaf(acc.w + sv.w, d, bgv.w);
    reinterpret_cast<float4*>(agg)[((size_t)c * NN + n) * 4 + l4] = o;
}

// ---------------------------------------------------------------- mean pool (batch sorted -> binary search bounds)
__device__ __forceinline__ int lower_bound_dev(const int* __restrict__ b, int v) {
    int lo = 0, hi = NN;
    while (lo < hi) {
        int m = (lo + hi) >> 1;
        if (b[m] < v) lo = m + 1; else hi = m;
    }
    return lo;
}

__global__ __launch_bounds__(128) void k_pool(const int* __restrict__ batch,
                                              const float* __restrict__ agg,  // chunk-major
                                              float* __restrict__ pooled,
                                              float* __restrict__ gcnt) {
    int g = blockIdx.x >> 3;   // 8 blocks per graph
    int q = blockIdx.x & 7;
    int tid = threadIdx.x;     // feature index f = (tid>>4)*16 + (tid&15) = tid
    int s = lower_bound_dev(batch, g);
    int e = lower_bound_dev(batch, g + 1);
    const float* __restrict__ ac = agg + (size_t)(tid >> 4) * NN * CHW + (tid & 15);
    float sum = 0.f;
    for (int n = s + q; n < e; n += 8)
        sum += fmaxf(ac[(size_t)n * CHW], 0.f);   // ReLU fused
    atomicAdd(&pooled[g * H + tid], sum);
    if (q == 0 && tid == 0) gcnt[g] = (float)(e - s);
}

// ---------------------------------------------------------------- LSTM (single step, h0=c0=0) + output head, fused
__global__ __launch_bounds__(256) void k_lstm(const float* __restrict__ pooled,
                                              const float* __restrict__ gcnt,
                                              const float* __restrict__ W_ih,
                                              const float* __restrict__ b_ih,
                                              const float* __restrict__ b_hh,
                                              const float* __restrict__ W_out,
                                              const float* __restrict__ b_out,
                                              float* __restrict__ out) {
    __shared__ __align__(16) float p[H];
    __shared__ __align__(16) float hn[LH];
    int g = blockIdx.x, t = threadIdx.x;
    if (t < H) p[t] = pooled[g * H + t] / fmaxf(gcnt[g], 1.f);
    __syncthreads();

    // gate rows (torch order i,f,g,o): f unused (c0=0)
    float si = b_ih[t] + b_hh[t];
    float sg = b_ih[2 * LH + t] + b_hh[2 * LH + t];
    float so = b_ih[3 * LH + t] + b_hh[3 * LH + t];
    const float* wi = W_ih + (size_t)t * H;
    const float* wg = W_ih + (size_t)(2 * LH + t) * H;
    const float* wo = W_ih + (size_t)(3 * LH + t) * H;
    for (int k = 0; k < H; k += 4) {
        float4 pv = *reinterpret_cast<const float4*>(&p[k]);
        float4 a = *reinterpret_cast<const float4*>(wi + k);
        si += pv.x * a.x + pv.y * a.y + pv.z * a.z + pv.w * a.w;
        float4 b = *reinterpret_cast<const float4*>(wg + k);
        sg += pv.x * b.x + pv.y * b.y + pv.z * b.z + pv.w * b.w;
        float4 c = *reinterpret_cast<const float4*>(wo + k);
        so += pv.x * c.x + pv.y * c.y + pv.z * c.z + pv.w * c.w;
    }
    float ig = 1.f / (1.f + expf(-si));
    float cc = ig * tanhf(sg);
    float og = 1.f / (1.f + expf(-so));
    hn[t] = og * tanhf(cc);
    __syncthreads();

    if (t < OD) {
        float acc = b_out[t];
        const float* wr = W_out + (size_t)t * LH;
        for (int k = 0; k < LH; k += 4) {
            float4 hv = *reinterpret_cast<const float4*>(&hn[k]);
            float4 wv = *reinterpret_cast<const float4*>(wr + k);
            acc += hv.x * wv.x + hv.y * wv.y + hv.z * wv.z + hv.w * wv.w;
        }
        out[g * OD + t] = acc;
    }
}

// ----------------------------------------------------------------
extern "C" void kernel_launch(void* const* d_in, const int* in_sizes, int n_in,
                              void* d_out, int out_size, void* d_ws, size_t ws_size,
                              hipStream_t stream) {
    const float* x     = (const float*)d_in[0];
    const int*   ei    = (const int*)d_in[1];   // [2][NE]: rows then cols
    const int*   batch = (const int*)d_in[2];
    const float* Wg    = (const float*)d_in[3]; // [3][128][128]
    const float* bg    = (const float*)d_in[4]; // [3][128]
    const float* W_ih  = (const float*)d_in[5]; // [1024][128]
    const float* b_ih  = (const float*)d_in[7];
    const float* b_hh  = (const float*)d_in[8];
    const float* W_out = (const float*)d_in[9]; // [32][256]
    const float* b_out = (const float*)d_in[10];
    float* out = (float*)d_out;

    // workspace layout (~71 MB)
    float* ws        = (float*)d_ws;
    float* buf0      = ws;                           // NN*H  (t', chunk-major)
    float* buf1      = buf0 + (size_t)NN * H;        // NN*H  (agg, chunk-major)
    int2*  part      = (int2*)(buf1 + (size_t)NN * H); // NE int2 (8B-aligned)
    float* dinv      = (float*)(part + NE);          // NN
    float* pooled    = dinv + NN;                    // NG*H
    float* gcnt      = pooled + NG * H;              // NG
    int*   cnt       = (int*)(gcnt + NG);            // NN
    int*   rp        = cnt + NN;                     // NN
    int*   srcs      = rp + NN;                      // NE
    int*   bktCnt    = srcs + NE;                    // NBKT
    int*   bktBase   = bktCnt + NBKT;                // NBKT+1
    int*   bktCursor = bktBase + NBKT + 1;           // NBKT

    hipMemsetAsync(bktCnt, 0, NBKT * sizeof(int), stream);
    hipMemsetAsync(pooled, 0, (NG * H + NG) * sizeof(float), stream);

    // CSR build (by destination) — bucketed counting sort
    k_bhist<<<256, 256, 0, stream>>>(ei + NE, bktCnt);
    k_bscan<<<1, 256, 0, stream>>>(bktCnt, bktBase, bktCursor);
    k_part <<<NPARTB, 256, 0, stream>>>(ei, bktCursor, part);
    k_bfill<<<NBKT, 256, 0, stream>>>(bktBase, part, rp, cnt, dinv, srcs);

    const int gemmBlocks = (NN + 63) / 64;
    const int gathBlocks = ((NN + 63) / 64) * NCH;   // 782 * 8 = 6256

    // layer 0: x (row-major) -> buf0 -> buf1
    k_gemm<false, false><<<gemmBlocks, 256, 0, stream>>>(x, Wg, dinv, buf0);
    k_gather<<<gathBlocks, 256, 0, stream>>>(rp, cnt, srcs, dinv, bg, buf0, buf1);
    // layer 1: relu(buf1) -> buf0 -> buf1
    k_gemm<true, true><<<gemmBlocks, 256, 0, stream>>>(buf1, Wg + H * H, dinv, buf0);
    k_gather<<<gathBlocks, 256, 0, stream>>>(rp, cnt, srcs, dinv, bg + H, buf0, buf1);
    // layer 2: relu(buf1) -> buf0 -> buf1
    k_gemm<true, true><<<gemmBlocks, 256, 0, stream>>>(buf1, Wg + 2 * H * H, dinv, buf0);
    k_gather<<<gathBlocks, 256, 0, stream>>>(rp, cnt, srcs, dinv, bg + 2 * H, buf0, buf1);

    k_pool<<<NG * 8, 128, 0, stream>>>(batch, buf1, pooled, gcnt);
    k_lstm<<<NG, 256, 0, stream>>>(pooled, gcnt, W_ih, b_ih, b_hh, W_out, b_out, out);
}

// Round 10
// 477.947 us; speedup vs baseline: 2.0176x; 1.2189x over previous
//
#include <hip/hip_runtime.h>

// Problem constants (match reference setup_inputs)
constexpr int NN = 50000;     // nodes
constexpr int NE = 1600000;   // edges
constexpr int H  = 128;       // feature dim (F_IN == H)
constexpr int LH = 256;       // lstm hidden
constexpr int OD = 32;        // output dim
constexpr int NG = 64;        // graphs

// Bucketed CSR build: bucket = dst >> 8 (256 nodes per bucket)
constexpr int NBKT  = (NN + 255) / 256;           // 196
constexpr int PARTE = 4096;                       // edges per k_part block
constexpr int NPARTB = (NE + PARTE - 1) / PARTE;  // 391
static_assert(NBKT <= 256, "single-block scan assumes NBKT <= 256");

// Feature chunking: 8 chunks x 16 floats. t'/agg stored as tc[(c*NN+n)*16+fl].
// Gather blocks with chunk==blockIdx&7 land on one XCD (round-robin heuristic)
// -> per-XCD L2 working set = NN*64B = 3.2 MB < 4 MB.
constexpr int NCH = 8;
constexpr int CHW = 16;

// LDS-staged edge window per gather block (ints). 64 nodes * avg deg 32 ~ 2048;
// 4608 is ~45 sigma. Fallback path covers the (astronomically rare) overflow.
constexpr int LSZ = 4608;

// ---------------------------------------------------------------- pass A: bucket histogram (LDS-aggregated)
__global__ __launch_bounds__(256) void k_bhist(const int* __restrict__ col,
                                               int* __restrict__ bktCnt) {
    __shared__ int h[NBKT];
    int t = threadIdx.x;
    if (t < NBKT) h[t] = 0;
    __syncthreads();
    for (int i = blockIdx.x * 256 + t; i < NE; i += gridDim.x * 256)
        atomicAdd(&h[col[i] >> 8], 1);
    __syncthreads();
    if (t < NBKT && h[t] > 0) atomicAdd(&bktCnt[t], h[t]);
}

// ---------------------------------------------------------------- pass B: scan bucket counts
__global__ __launch_bounds__(256) void k_bscan(const int* __restrict__ bktCnt,
                                               int* __restrict__ bktBase,
                                               int* __restrict__ bktCursor) {
    __shared__ int sh[256];
    int t = threadIdx.x;
    int v = (t < NBKT) ? bktCnt[t] : 0;
    sh[t] = v;
    __syncthreads();
    for (int off = 1; off < 256; off <<= 1) {
        int add = (t >= off) ? sh[t - off] : 0;
        __syncthreads();
        sh[t] += add;
        __syncthreads();
    }
    if (t < NBKT) {
        int excl = sh[t] - v;
        bktBase[t] = excl;
        bktCursor[t] = excl;
    }
    if (t == NBKT - 1) bktBase[NBKT] = sh[t];
}

// ---------------------------------------------------------------- pass C: partition edges into bucket-ordered (src,dst)
__global__ __launch_bounds__(256) void k_part(const int* __restrict__ ei,
                                              int* __restrict__ bktCursor,
                                              int2* __restrict__ part) {
    __shared__ int lcur[NBKT];
    __shared__ int lbase[NBKT];
    const int t = threadIdx.x;
    const int base = blockIdx.x * PARTE;
    int sr[16], ds[16], bk[16];

    if (t < NBKT) lcur[t] = 0;
    __syncthreads();
#pragma unroll
    for (int j = 0; j < 16; ++j) {
        int e = base + j * 256 + t;
        if (e < NE) {
            sr[j] = ei[e];
            ds[j] = ei[NE + e];
            bk[j] = ds[j] >> 8;
            atomicAdd(&lcur[bk[j]], 1);
        }
    }
    __syncthreads();
    if (t < NBKT) {
        int c = lcur[t];
        lbase[t] = (c > 0) ? atomicAdd(&bktCursor[t], c) : 0;
        lcur[t] = 0;
    }
    __syncthreads();
#pragma unroll
    for (int j = 0; j < 16; ++j) {
        int e = base + j * 256 + t;
        if (e < NE) {
            int r = atomicAdd(&lcur[bk[j]], 1);
            part[lbase[bk[j]] + r] = make_int2(sr[j], ds[j]);
        }
    }
}

// ---------------------------------------------------------------- pass D: per-bucket CSR finalize (all atomics in LDS)
__global__ __launch_bounds__(256) void k_bfill(const int* __restrict__ bktBase,
                                               const int2* __restrict__ part,
                                               int* __restrict__ rp,
                                               int* __restrict__ cnt,
                                               float* __restrict__ dinv,
                                               int* __restrict__ srcs) {
    __shared__ int h[256];
    __shared__ int sc[256];
    __shared__ int cur[256];
    const int b = blockIdx.x, t = threadIdx.x;
    const int lo = bktBase[b], hi = bktBase[b + 1];

    h[t] = 0;
    __syncthreads();
    for (int i = lo + t; i < hi; i += 256)
        atomicAdd(&h[part[i].y & 255], 1);
    __syncthreads();
    int v = h[t];
    sc[t] = v;
    __syncthreads();
    for (int off = 1; off < 256; off <<= 1) {
        int add = (t >= off) ? sc[t - off] : 0;
        __syncthreads();
        sc[t] += add;
        __syncthreads();
    }
    int excl = sc[t] - v;
    cur[t] = lo + excl;
    int node = b * 256 + t;
    if (node < NN) {
        rp[node] = lo + excl;
        cnt[node] = v;
        dinv[node] = rsqrtf((float)v + 1.0f);   // self-loop adds 1
    }
    __syncthreads();
    for (int i = lo + t; i < hi; i += 256) {
        int2 e = part[i];
        int pos = atomicAdd(&cur[e.y & 255], 1);
        srcs[pos] = e.x;
    }
}

// ---------------------------------------------------------------- GEMM t' = (relu?)(h) @ W * dinv[row]
// Output chunk-major. Input row-major (layer 0: x) or chunk-major (agg).
template <bool RELU, bool CHIN>
__global__ __launch_bounds__(256) void k_gemm(const float* __restrict__ h,
                                              const float* __restrict__ W,
                                              const float* __restrict__ dinv,
                                              float* __restrict__ t) {
    const int tid  = threadIdx.x;
    const int lane = tid & 63;
    const int wave = tid >> 6;
    const int colg = lane & 31;                 // 0..31 -> cols colg*4..+3
    const int rowg = (wave << 1) | (lane >> 5); // 0..7  -> 8 rows each
    const int rb   = blockIdx.x * 64 + rowg * 8;

    const float4* __restrict__ W4 = reinterpret_cast<const float4*>(W);

    float4 acc[8];
#pragma unroll
    for (int r = 0; r < 8; ++r) acc[r] = make_float4(0.f, 0.f, 0.f, 0.f);

    int rowid[8];
#pragma unroll
    for (int r = 0; r < 8; ++r) {
        int rr   = rb + r;
        rowid[r] = rr < NN ? rr : NN - 1;   // clamp loads, guard stores
    }

    for (int k0 = 0; k0 < H; k0 += 4) {
        float4 wv0 = W4[(k0 + 0) * 32 + colg];
        float4 wv1 = W4[(k0 + 1) * 32 + colg];
        float4 wv2 = W4[(k0 + 2) * 32 + colg];
        float4 wv3 = W4[(k0 + 3) * 32 + colg];
#pragma unroll
        for (int r = 0; r < 8; ++r) {
            float4 hv;
            if (CHIN) {
                // chunk-major: floats k0..k0+3 live in chunk k0>>4 at offset k0&12
                hv = *reinterpret_cast<const float4*>(
                    h + ((size_t)(k0 >> 4) * NN + rowid[r]) * CHW + (k0 & 12));
            } else {
                hv = *reinterpret_cast<const float4*>(h + (size_t)rowid[r] * H + k0);
            }
            if (RELU) {
                hv.x = fmaxf(hv.x, 0.f); hv.y = fmaxf(hv.y, 0.f);
                hv.z = fmaxf(hv.z, 0.f); hv.w = fmaxf(hv.w, 0.f);
            }
            acc[r].x = fmaf(hv.x, wv0.x, fmaf(hv.y, wv1.x, fmaf(hv.z, wv2.x, fmaf(hv.w, wv3.x, acc[r].x))));
            acc[r].y = fmaf(hv.x, wv0.y, fmaf(hv.y, wv1.y, fmaf(hv.z, wv2.y, fmaf(hv.w, wv3.y, acc[r].y))));
            acc[r].z = fmaf(hv.x, wv0.z, fmaf(hv.y, wv1.z, fmaf(hv.z, wv2.z, fmaf(hv.w, wv3.z, acc[r].z))));
            acc[r].w = fmaf(hv.x, wv0.w, fmaf(hv.y, wv1.w, fmaf(hv.z, wv2.w, fmaf(hv.w, wv3.w, acc[r].w))));
        }
    }

#pragma unroll
    for (int r = 0; r < 8; ++r) {
        int rr = rb + r;
        if (rr < NN) {
            float d = dinv[rr];
            acc[r].x *= d; acc[r].y *= d; acc[r].z *= d; acc[r].w *= d;
            // chunk-major store: cols colg*4..+3 -> chunk colg>>2, offset (colg&3)*4
            *reinterpret_cast<float4*>(
                t + ((size_t)(colg >> 2) * NN + rr) * CHW + (colg & 3) * 4) = acc[r];
        }
    }
}

// ---------------------------------------------------------------- gather (chunk-major, LDS-staged indices):
// agg_c[n] = bg_c + dinv[n] * (t_c[n] + sum_e t_c[src[e]])
// Block = 64 nodes x 1 chunk. Stage the block's contiguous srcs window into
// LDS (coalesced), then 4-lane groups walk indices from LDS and issue row
// loads unroll-8 back-to-back -> deep MLP, no srcs->row global latency chain.
__global__ __launch_bounds__(256) void k_gather(const int* __restrict__ rp,
                                                const int* __restrict__ cnt,
                                                const int* __restrict__ srcs,
                                                const float* __restrict__ dinv,
                                                const float* __restrict__ bg,
                                                const float* __restrict__ t,
                                                float* __restrict__ agg) {
    __shared__ int lsrcs[LSZ];
    const int tid  = threadIdx.x;
    const int wv   = tid >> 6;         // 0..3
    const int lane = tid & 63;
    const int slot = lane >> 2;        // node group 0..15
    const int l4   = lane & 3;         // float4 index within 64B row
    const int c    = blockIdx.x & 7;   // chunk (-> XCD via round-robin heuristic)
    const int nb   = blockIdx.x >> 3;  // node block (64 nodes)
    const int n0   = nb * 64;
    const int n    = n0 + wv * 16 + slot;

    // block's contiguous edge window
    const int eLo = rp[n0];
    int nLast = n0 + 63; if (nLast >= NN) nLast = NN - 1;
    const int eHi = rp[nLast] + cnt[nLast];
    const bool staged = (eHi - eLo) <= LSZ;   // block-uniform

    if (staged) {
        for (int i = eLo + tid; i < eHi; i += 256)
            lsrcs[i - eLo] = srcs[i];
    }
    __syncthreads();

    if (n >= NN) return;

    const float4* __restrict__ tc4 =
        reinterpret_cast<const float4*>(t + (size_t)c * NN * CHW);
    const float4 bgv = reinterpret_cast<const float4*>(bg + c * CHW)[l4];

    const int i0  = rp[n];
    const int end = i0 + cnt[n];
    float4 acc = make_float4(0.f, 0.f, 0.f, 0.f);

    if (staged) {
        int i = i0;
        // indices come from LDS (cheap); 8 independent row loads in flight
        for (; i + 7 < end; i += 8) {
            int s0 = lsrcs[i     - eLo], s1 = lsrcs[i + 1 - eLo];
            int s2 = lsrcs[i + 2 - eLo], s3 = lsrcs[i + 3 - eLo];
            int s4 = lsrcs[i + 4 - eLo], s5 = lsrcs[i + 5 - eLo];
            int s6 = lsrcs[i + 6 - eLo], s7 = lsrcs[i + 7 - eLo];
            float4 v0 = tc4[(size_t)s0 * 4 + l4];
            float4 v1 = tc4[(size_t)s1 * 4 + l4];
            float4 v2 = tc4[(size_t)s2 * 4 + l4];
            float4 v3 = tc4[(size_t)s3 * 4 + l4];
            float4 v4 = tc4[(size_t)s4 * 4 + l4];
            float4 v5 = tc4[(size_t)s5 * 4 + l4];
            float4 v6 = tc4[(size_t)s6 * 4 + l4];
            float4 v7 = tc4[(size_t)s7 * 4 + l4];
            acc.x += ((v0.x + v1.x) + (v2.x + v3.x)) + ((v4.x + v5.x) + (v6.x + v7.x));
            acc.y += ((v0.y + v1.y) + (v2.y + v3.y)) + ((v4.y + v5.y) + (v6.y + v7.y));
            acc.z += ((v0.z + v1.z) + (v2.z + v3.z)) + ((v4.z + v5.z) + (v6.z + v7.z));
            acc.w += ((v0.w + v1.w) + (v2.w + v3.w)) + ((v4.w + v5.w) + (v6.w + v7.w));
        }
        for (; i < end; ++i) {
            int s = lsrcs[i - eLo];
            float4 v = tc4[(size_t)s * 4 + l4];
            acc.x += v.x; acc.y += v.y; acc.z += v.z; acc.w += v.w;
        }
    } else {
        // fallback (rare): walk global srcs, unroll-4
        int i = i0;
        for (; i + 3 < end; i += 4) {
            int s0 = srcs[i], s1 = srcs[i + 1], s2 = srcs[i + 2], s3 = srcs[i + 3];
            float4 v0 = tc4[(size_t)s0 * 4 + l4];
            float4 v1 = tc4[(size_t)s1 * 4 + l4];
            float4 v2 = tc4[(size_t)s2 * 4 + l4];
            float4 v3 = tc4[(size_t)s3 * 4 + l4];
            acc.x += (v0.x + v1.x) + (v2.x + v3.x);
            acc.y += (v0.y + v1.y) + (v2.y + v3.y);
            acc.z += (v0.z + v1.z) + (v2.z + v3.z);
            acc.w += (v0.w + v1.w) + (v2.w + v3.w);
        }
        for (; i < end; ++i) {
            int s = srcs[i];
            float4 v = tc4[(size_t)s * 4 + l4];
            acc.x += v.x; acc.y += v.y; acc.z += v.z; acc.w += v.w;
        }
    }

    float4 sv = tc4[(size_t)n * 4 + l4];   // self-loop term
    float d = dinv[n];
    float4 o;
    o.x = fmaf(acc.x + sv.x, d, bgv.x);
    o.y = fmaf(acc.y + sv.y, d, bgv.y);
    o.z = fmaf(acc.z + sv.z, d, bgv.z);
    o.w = fmaf(acc.w + sv.w, d, bgv.w);
    reinterpret_cast<float4*>(agg)[((size_t)c * NN + n) * 4 + l4] = o;
}

// ---------------------------------------------------------------- mean pool (batch sorted -> binary search bounds)
__device__ __forceinline__ int lower_bound_dev(const int* __restrict__ b, int v) {
    int lo = 0, hi = NN;
    while (lo < hi) {
        int m = (lo + hi) >> 1;
        if (b[m] < v) lo = m + 1; else hi = m;
    }
    return lo;
}

__global__ __launch_bounds__(128) void k_pool(const int* __restrict__ batch,
                                              const float* __restrict__ agg,  // chunk-major
                                              float* __restrict__ pooled,
                                              float* __restrict__ gcnt) {
    int g = blockIdx.x >> 3;   // 8 blocks per graph
    int q = blockIdx.x & 7;
    int tid = threadIdx.x;     // feature index f = (tid>>4)*16 + (tid&15) = tid
    int s = lower_bound_dev(batch, g);
    int e = lower_bound_dev(batch, g + 1);
    const float* __restrict__ ac = agg + (size_t)(tid >> 4) * NN * CHW + (tid & 15);
    float sum = 0.f;
    for (int n = s + q; n < e; n += 8)
        sum += fmaxf(ac[(size_t)n * CHW], 0.f);   // ReLU fused
    atomicAdd(&pooled[g * H + tid], sum);
    if (q == 0 && tid == 0) gcnt[g] = (float)(e - s);
}

// ---------------------------------------------------------------- LSTM (single step, h0=c0=0) + output head, fused
__global__ __launch_bounds__(256) void k_lstm(const float* __restrict__ pooled,
                                              const float* __restrict__ gcnt,
                                              const float* __restrict__ W_ih,
                                              const float* __restrict__ b_ih,
                                              const float* __restrict__ b_hh,
                                              const float* __restrict__ W_out,
                                              const float* __restrict__ b_out,
                                              float* __restrict__ out) {
    __shared__ __align__(16) float p[H];
    __shared__ __align__(16) float hn[LH];
    int g = blockIdx.x, t = threadIdx.x;
    if (t < H) p[t] = pooled[g * H + t] / fmaxf(gcnt[g], 1.f);
    __syncthreads();

    // gate rows (torch order i,f,g,o): f unused (c0=0)
    float si = b_ih[t] + b_hh[t];
    float sg = b_ih[2 * LH + t] + b_hh[2 * LH + t];
    float so = b_ih[3 * LH + t] + b_hh[3 * LH + t];
    const float* wi = W_ih + (size_t)t * H;
    const float* wg = W_ih + (size_t)(2 * LH + t) * H;
    const float* wo = W_ih + (size_t)(3 * LH + t) * H;
    for (int k = 0; k < H; k += 4) {
        float4 pv = *reinterpret_cast<const float4*>(&p[k]);
        float4 a = *reinterpret_cast<const float4*>(wi + k);
        si += pv.x * a.x + pv.y * a.y + pv.z * a.z + pv.w * a.w;
        float4 b = *reinterpret_cast<const float4*>(wg + k);
        sg += pv.x * b.x + pv.y * b.y + pv.z * b.z + pv.w * b.w;
        float4 c = *reinterpret_cast<const float4*>(wo + k);
        so += pv.x * c.x + pv.y * c.y + pv.z * c.z + pv.w * c.w;
    }
    float ig = 1.f / (1.f + expf(-si));
    float cc = ig * tanhf(sg);
    float og = 1.f / (1.f + expf(-so));
    hn[t] = og * tanhf(cc);
    __syncthreads();

    if (t < OD) {
        float acc = b_out[t];
        const float* wr = W_out + (size_t)t * LH;
        for (int k = 0; k < LH; k += 4) {
            float4 hv = *reinterpret_cast<const float4*>(&hn[k]);
            float4 wv = *reinterpret_cast<const float4*>(wr + k);
            acc += hv.x * wv.x + hv.y * wv.y + hv.z * wv.z + hv.w * wv.w;
        }
        out[g * OD + t] = acc;
    }
}

// ----------------------------------------------------------------
extern "C" void kernel_launch(void* const* d_in, const int* in_sizes, int n_in,
                              void* d_out, int out_size, void* d_ws, size_t ws_size,
                              hipStream_t stream) {
    const float* x     = (const float*)d_in[0];
    const int*   ei    = (const int*)d_in[1];   // [2][NE]: rows then cols
    const int*   batch = (const int*)d_in[2];
    const float* Wg    = (const float*)d_in[3]; // [3][128][128]
    const float* bg    = (const float*)d_in[4]; // [3][128]
    const float* W_ih  = (const float*)d_in[5]; // [1024][128]
    const float* b_ih  = (const float*)d_in[7];
    const float* b_hh  = (const float*)d_in[8];
    const float* W_out = (const float*)d_in[9]; // [32][256]
    const float* b_out = (const float*)d_in[10];
    float* out = (float*)d_out;

    // workspace layout (~71 MB)
    float* ws        = (float*)d_ws;
    float* buf0      = ws;                           // NN*H  (t', chunk-major)
    float* buf1      = buf0 + (size_t)NN * H;        // NN*H  (agg, chunk-major)
    int2*  part      = (int2*)(buf1 + (size_t)NN * H); // NE int2 (8B-aligned)
    float* dinv      = (float*)(part + NE);          // NN
    float* pooled    = dinv + NN;                    // NG*H
    float* gcnt      = pooled + NG * H;              // NG
    int*   cnt       = (int*)(gcnt + NG);            // NN
    int*   rp        = cnt + NN;                     // NN
    int*   srcs      = rp + NN;                      // NE
    int*   bktCnt    = srcs + NE;                    // NBKT
    int*   bktBase   = bktCnt + NBKT;                // NBKT+1
    int*   bktCursor = bktBase + NBKT + 1;           // NBKT

    hipMemsetAsync(bktCnt, 0, NBKT * sizeof(int), stream);
    hipMemsetAsync(pooled, 0, (NG * H + NG) * sizeof(float), stream);

    // CSR build (by destination) — bucketed counting sort
    k_bhist<<<256, 256, 0, stream>>>(ei + NE, bktCnt);
    k_bscan<<<1, 256, 0, stream>>>(bktCnt, bktBase, bktCursor);
    k_part <<<NPARTB, 256, 0, stream>>>(ei, bktCursor, part);
    k_bfill<<<NBKT, 256, 0, stream>>>(bktBase, part, rp, cnt, dinv, srcs);

    const int gemmBlocks = (NN + 63) / 64;
    const int gathBlocks = ((NN + 63) / 64) * NCH;   // 782 * 8 = 6256

    // layer 0: x (row-major) -> buf0 -> buf1
    k_gemm<false, false><<<gemmBlocks, 256, 0, stream>>>(x, Wg, dinv, buf0);
    k_gather<<<gathBlocks, 256, 0, stream>>>(rp, cnt, srcs, dinv, bg, buf0, buf1);
    // layer 1: relu(buf1) -> buf0 -> buf1
    k_gemm<true, true><<<gemmBlocks, 256, 0, stream>>>(buf1, Wg + H * H, dinv, buf0);
    k_gather<<<gathBlocks, 256, 0, stream>>>(rp, cnt, srcs, dinv, bg + H, buf0, buf1);
    // layer 2: relu(buf1) -> buf0 -> buf1
    k_gemm<true, true><<<gemmBlocks, 256, 0, stream>>>(buf1, Wg + 2 * H * H, dinv, buf0);
    k_gather<<<gathBlocks, 256, 0, stream>>>(rp, cnt, srcs, dinv, bg + 2 * H, buf0, buf1);

    k_pool<<<NG * 8, 128, 0, stream>>>(batch, buf1, pooled, gcnt);
    k_lstm<<<NG, 256, 0, stream>>>(pooled, gcnt, W_ih, b_ih, b_hh, W_out, b_out, out);
}

// Round 11
// 405.705 us; speedup vs baseline: 2.3768x; 1.1781x over previous
//
#include <hip/hip_runtime.h>

// Problem constants (match reference setup_inputs)
constexpr int NN = 50000;     // nodes
constexpr int NE = 1600000;   // edges
constexpr int H  = 128;       // feature dim (F_IN == H)
constexpr int LH = 256;       // lstm hidden
constexpr int OD = 32;        // output dim
constexpr int NG = 64;        // graphs

// Bucketed CSR build: bucket = dst >> 8 (256 nodes per bucket)
constexpr int NBKT  = (NN + 255) / 256;           // 196
constexpr int PARTE = 4096;                       // edges per k_part block
constexpr int NPARTB = (NE + PARTE - 1) / PARTE;  // 391
static_assert(NBKT <= 256, "single-block scan assumes NBKT <= 256");

// agg layout: fp32 chunk-major, 8 chunks x 16 floats (pool/GEMM input).
constexpr int NCH = 8;
constexpr int CHW = 16;
// t' layout: bf16 chunk-major, 4 chunks x 32 bf16 (one 64B line per chunk-row).
// Gather: chunk = blockIdx&3 -> XCDs {c, c+4}; per-XCD set = NN*64B = 3.2MB < 4MB.
constexpr int BCH = 4;
constexpr int BCW = 32;

// LDS-staged edge window per gather block (ints). 64 nodes * avg 32 ~ 2048.
constexpr int LSZ = 4608;

__device__ __forceinline__ unsigned short f2bf(float x) {
    unsigned int u = __float_as_uint(x);
    u = (u + 0x7FFFu + ((u >> 16) & 1u)) >> 16;   // round-to-nearest-even
    return (unsigned short)u;
}

// ---------------------------------------------------------------- pass A: bucket histogram (LDS-aggregated)
__global__ __launch_bounds__(256) void k_bhist(const int* __restrict__ col,
                                               int* __restrict__ bktCnt) {
    __shared__ int h[NBKT];
    int t = threadIdx.x;
    if (t < NBKT) h[t] = 0;
    __syncthreads();
    for (int i = blockIdx.x * 256 + t; i < NE; i += gridDim.x * 256)
        atomicAdd(&h[col[i] >> 8], 1);
    __syncthreads();
    if (t < NBKT && h[t] > 0) atomicAdd(&bktCnt[t], h[t]);
}

// ---------------------------------------------------------------- pass B: scan bucket counts
__global__ __launch_bounds__(256) void k_bscan(const int* __restrict__ bktCnt,
                                               int* __restrict__ bktBase,
                                               int* __restrict__ bktCursor) {
    __shared__ int sh[256];
    int t = threadIdx.x;
    int v = (t < NBKT) ? bktCnt[t] : 0;
    sh[t] = v;
    __syncthreads();
    for (int off = 1; off < 256; off <<= 1) {
        int add = (t >= off) ? sh[t - off] : 0;
        __syncthreads();
        sh[t] += add;
        __syncthreads();
    }
    if (t < NBKT) {
        int excl = sh[t] - v;
        bktBase[t] = excl;
        bktCursor[t] = excl;
    }
    if (t == NBKT - 1) bktBase[NBKT] = sh[t];
}

// ---------------------------------------------------------------- pass C: partition edges, packed (src<<8 | dst&255)
__global__ __launch_bounds__(256) void k_part(const int* __restrict__ ei,
                                              int* __restrict__ bktCursor,
                                              int* __restrict__ part) {
    __shared__ int lcur[NBKT];
    __shared__ int lbase[NBKT];
    const int t = threadIdx.x;
    const int base = blockIdx.x * PARTE;
    int pk[16], bk[16];

    if (t < NBKT) lcur[t] = 0;
    __syncthreads();
#pragma unroll
    for (int j = 0; j < 16; ++j) {
        int e = base + j * 256 + t;
        if (e < NE) {
            int sr = ei[e];
            int ds = ei[NE + e];
            pk[j] = (sr << 8) | (ds & 255);
            bk[j] = ds >> 8;
            atomicAdd(&lcur[bk[j]], 1);
        }
    }
    __syncthreads();
    if (t < NBKT) {
        int c = lcur[t];
        lbase[t] = (c > 0) ? atomicAdd(&bktCursor[t], c) : 0;
        lcur[t] = 0;
    }
    __syncthreads();
#pragma unroll
    for (int j = 0; j < 16; ++j) {
        int e = base + j * 256 + t;
        if (e < NE) {
            int r = atomicAdd(&lcur[bk[j]], 1);
            part[lbase[bk[j]] + r] = pk[j];
        }
    }
}

// ---------------------------------------------------------------- pass D: per-bucket CSR finalize (all atomics in LDS)
__global__ __launch_bounds__(256) void k_bfill(const int* __restrict__ bktBase,
                                               const int* __restrict__ part,
                                               int* __restrict__ rp,
                                               int* __restrict__ cnt,
                                               float* __restrict__ dinv,
                                               int* __restrict__ srcs) {
    __shared__ int h[256];
    __shared__ int sc[256];
    __shared__ int cur[256];
    const int b = blockIdx.x, t = threadIdx.x;
    const int lo = bktBase[b], hi = bktBase[b + 1];

    h[t] = 0;
    __syncthreads();
    for (int i = lo + t; i < hi; i += 256)
        atomicAdd(&h[part[i] & 255], 1);
    __syncthreads();
    int v = h[t];
    sc[t] = v;
    __syncthreads();
    for (int off = 1; off < 256; off <<= 1) {
        int add = (t >= off) ? sc[t - off] : 0;
        __syncthreads();
        sc[t] += add;
        __syncthreads();
    }
    int excl = sc[t] - v;
    cur[t] = lo + excl;
    int node = b * 256 + t;
    if (node < NN) {
        rp[node] = lo + excl;
        cnt[node] = v;
        dinv[node] = rsqrtf((float)v + 1.0f);   // self-loop adds 1
    }
    __syncthreads();
    for (int i = lo + t; i < hi; i += 256) {
        int e = part[i];
        int pos = atomicAdd(&cur[e & 255], 1);
        srcs[pos] = e >> 8;
    }
}

// ---------------------------------------------------------------- GEMM t' = (relu?)(h) @ W * dinv[row], bf16 out
// Input row-major fp32 (layer 0: x) or fp32 chunk-major CHW=16 (agg).
// Output: bf16 chunk-major BCH=4 x BCW=32.
template <bool RELU, bool CHIN>
__global__ __launch_bounds__(256) void k_gemm(const float* __restrict__ h,
                                              const float* __restrict__ W,
                                              const float* __restrict__ dinv,
                                              unsigned short* __restrict__ tb) {
    const int tid  = threadIdx.x;
    const int lane = tid & 63;
    const int wave = tid >> 6;
    const int colg = lane & 31;                 // 0..31 -> cols colg*4..+3
    const int rowg = (wave << 1) | (lane >> 5); // 0..7  -> 8 rows each
    const int rb   = blockIdx.x * 64 + rowg * 8;

    const float4* __restrict__ W4 = reinterpret_cast<const float4*>(W);

    float4 acc[8];
#pragma unroll
    for (int r = 0; r < 8; ++r) acc[r] = make_float4(0.f, 0.f, 0.f, 0.f);

    int rowid[8];
#pragma unroll
    for (int r = 0; r < 8; ++r) {
        int rr   = rb + r;
        rowid[r] = rr < NN ? rr : NN - 1;   // clamp loads, guard stores
    }

    for (int k0 = 0; k0 < H; k0 += 4) {
        float4 wv0 = W4[(k0 + 0) * 32 + colg];
        float4 wv1 = W4[(k0 + 1) * 32 + colg];
        float4 wv2 = W4[(k0 + 2) * 32 + colg];
        float4 wv3 = W4[(k0 + 3) * 32 + colg];
#pragma unroll
        for (int r = 0; r < 8; ++r) {
            float4 hv;
            if (CHIN) {
                hv = *reinterpret_cast<const float4*>(
                    h + ((size_t)(k0 >> 4) * NN + rowid[r]) * CHW + (k0 & 12));
            } else {
                hv = *reinterpret_cast<const float4*>(h + (size_t)rowid[r] * H + k0);
            }
            if (RELU) {
                hv.x = fmaxf(hv.x, 0.f); hv.y = fmaxf(hv.y, 0.f);
                hv.z = fmaxf(hv.z, 0.f); hv.w = fmaxf(hv.w, 0.f);
            }
            acc[r].x = fmaf(hv.x, wv0.x, fmaf(hv.y, wv1.x, fmaf(hv.z, wv2.x, fmaf(hv.w, wv3.x, acc[r].x))));
            acc[r].y = fmaf(hv.x, wv0.y, fmaf(hv.y, wv1.y, fmaf(hv.z, wv2.y, fmaf(hv.w, wv3.y, acc[r].y))));
            acc[r].z = fmaf(hv.x, wv0.z, fmaf(hv.y, wv1.z, fmaf(hv.z, wv2.z, fmaf(hv.w, wv3.z, acc[r].z))));
            acc[r].w = fmaf(hv.x, wv0.w, fmaf(hv.y, wv1.w, fmaf(hv.z, wv2.w, fmaf(hv.w, wv3.w, acc[r].w))));
        }
    }

#pragma unroll
    for (int r = 0; r < 8; ++r) {
        int rr = rb + r;
        if (rr < NN) {
            float d = dinv[rr];
            ushort4 o;
            o.x = f2bf(acc[r].x * d);
            o.y = f2bf(acc[r].y * d);
            o.z = f2bf(acc[r].z * d);
            o.w = f2bf(acc[r].w * d);
            // cols colg*4..+3 -> bf16 chunk colg>>3, offset (colg&7)*4 (8B store)
            *reinterpret_cast<ushort4*>(
                tb + ((size_t)(colg >> 3) * NN + rr) * BCW + (colg & 7) * 4) = o;
        }
    }
}

// ---------------------------------------------------------------- gather (bf16 rows, LDS-staged indices):
// agg = bg + dinv[n] * (t'[n] + sum_e t'[src[e]]) ; t' bf16, accum fp32.
// Block = 64 nodes x 1 bf16 chunk (32 feats, 64B row). 16 groups x 4 lanes;
// lane reads uint4 (8 bf16), unpacks, accumulates 8 fp32.
__global__ __launch_bounds__(256) void k_gather(const int* __restrict__ rp,
                                                const int* __restrict__ cnt,
                                                const int* __restrict__ srcs,
                                                const float* __restrict__ dinv,
                                                const float* __restrict__ bg,
                                                const unsigned short* __restrict__ tb,
                                                float* __restrict__ agg) {
    __shared__ int lsrcs[LSZ];
    const int tid  = threadIdx.x;
    const int wv   = tid >> 6;         // 0..3
    const int lane = tid & 63;
    const int slot = lane >> 2;        // node group 0..15
    const int l4   = lane & 3;         // uint4 index within 64B row
    const int c    = blockIdx.x & 3;   // bf16 chunk (-> XCDs {c, c+4})
    const int nb   = blockIdx.x >> 2;  // node block (64 nodes)
    const int n0   = nb * 64;
    const int n    = n0 + wv * 16 + slot;

    const int eLo = rp[n0];
    int nLast = n0 + 63; if (nLast >= NN) nLast = NN - 1;
    const int eHi = rp[nLast] + cnt[nLast];
    const bool staged = (eHi - eLo) <= LSZ;   // block-uniform

    if (staged) {
        for (int i = eLo + tid; i < eHi; i += 256)
            lsrcs[i - eLo] = srcs[i];
    }
    __syncthreads();

    if (n >= NN) return;

    const uint4* __restrict__ tb4 =
        reinterpret_cast<const uint4*>(tb) + (size_t)c * NN * 4;
    // lane covers features c*32 + l4*8 .. +7
    const float4 bg0 = *reinterpret_cast<const float4*>(bg + c * BCW + l4 * 8);
    const float4 bg1 = *reinterpret_cast<const float4*>(bg + c * BCW + l4 * 8 + 4);

    const int i0  = rp[n];
    const int end = i0 + cnt[n];
    float4 p = make_float4(0.f, 0.f, 0.f, 0.f);
    float4 q = make_float4(0.f, 0.f, 0.f, 0.f);

#define ACC8(v)                                                        \
    do {                                                               \
        p.x += __uint_as_float((v).x << 16);                           \
        p.y += __uint_as_float((v).x & 0xFFFF0000u);                   \
        p.z += __uint_as_float((v).y << 16);                           \
        p.w += __uint_as_float((v).y & 0xFFFF0000u);                   \
        q.x += __uint_as_float((v).z << 16);                           \
        q.y += __uint_as_float((v).z & 0xFFFF0000u);                   \
        q.z += __uint_as_float((v).w << 16);                           \
        q.w += __uint_as_float((v).w & 0xFFFF0000u);                   \
    } while (0)

    if (staged) {
        int i = i0;
        for (; i + 7 < end; i += 8) {
            int s0 = lsrcs[i     - eLo], s1 = lsrcs[i + 1 - eLo];
            int s2 = lsrcs[i + 2 - eLo], s3 = lsrcs[i + 3 - eLo];
            int s4 = lsrcs[i + 4 - eLo], s5 = lsrcs[i + 5 - eLo];
            int s6 = lsrcs[i + 6 - eLo], s7 = lsrcs[i + 7 - eLo];
            uint4 v0 = tb4[(size_t)s0 * 4 + l4];
            uint4 v1 = tb4[(size_t)s1 * 4 + l4];
            uint4 v2 = tb4[(size_t)s2 * 4 + l4];
            uint4 v3 = tb4[(size_t)s3 * 4 + l4];
            uint4 v4 = tb4[(size_t)s4 * 4 + l4];
            uint4 v5 = tb4[(size_t)s5 * 4 + l4];
            uint4 v6 = tb4[(size_t)s6 * 4 + l4];
            uint4 v7 = tb4[(size_t)s7 * 4 + l4];
            ACC8(v0); ACC8(v1); ACC8(v2); ACC8(v3);
            ACC8(v4); ACC8(v5); ACC8(v6); ACC8(v7);
        }
        for (; i < end; ++i) {
            uint4 v = tb4[(size_t)lsrcs[i - eLo] * 4 + l4];
            ACC8(v);
        }
    } else {
        int i = i0;
        for (; i + 3 < end; i += 4) {
            int s0 = srcs[i], s1 = srcs[i + 1], s2 = srcs[i + 2], s3 = srcs[i + 3];
            uint4 v0 = tb4[(size_t)s0 * 4 + l4];
            uint4 v1 = tb4[(size_t)s1 * 4 + l4];
            uint4 v2 = tb4[(size_t)s2 * 4 + l4];
            uint4 v3 = tb4[(size_t)s3 * 4 + l4];
            ACC8(v0); ACC8(v1); ACC8(v2); ACC8(v3);
        }
        for (; i < end; ++i) {
            uint4 v = tb4[(size_t)srcs[i] * 4 + l4];
            ACC8(v);
        }
    }

    uint4 sv = tb4[(size_t)n * 4 + l4];   // self-loop term
    ACC8(sv);
#undef ACC8

    const float d = dinv[n];
    float4 o0, o1;
    o0.x = fmaf(p.x, d, bg0.x); o0.y = fmaf(p.y, d, bg0.y);
    o0.z = fmaf(p.z, d, bg0.z); o0.w = fmaf(p.w, d, bg0.w);
    o1.x = fmaf(q.x, d, bg1.x); o1.y = fmaf(q.y, d, bg1.y);
    o1.z = fmaf(q.z, d, bg1.z); o1.w = fmaf(q.w, d, bg1.w);

    // agg fp32 chunk-major CHW=16: feature f = c*32 + l4*8 + j
    // -> fp32 chunk fc = 2c + (l4>>1), offset (l4&1)*8
    const int fc  = 2 * c + (l4 >> 1);
    float* dst = agg + ((size_t)fc * NN + n) * CHW + (l4 & 1) * 8;
    *reinterpret_cast<float4*>(dst)     = o0;
    *reinterpret_cast<float4*>(dst + 4) = o1;
}

// ---------------------------------------------------------------- mean pool (batch sorted -> binary search bounds)
__device__ __forceinline__ int lower_bound_dev(const int* __restrict__ b, int v) {
    int lo = 0, hi = NN;
    while (lo < hi) {
        int m = (lo + hi) >> 1;
        if (b[m] < v) lo = m + 1; else hi = m;
    }
    return lo;
}

__global__ __launch_bounds__(128) void k_pool(const int* __restrict__ batch,
                                              const float* __restrict__ agg,  // fp32 chunk-major
                                              float* __restrict__ pooled,
                                              float* __restrict__ gcnt) {
    int g = blockIdx.x >> 3;   // 8 blocks per graph
    int q = blockIdx.x & 7;
    int tid = threadIdx.x;     // feature index f = tid
    int s = lower_bound_dev(batch, g);
    int e = lower_bound_dev(batch, g + 1);
    const float* __restrict__ ac = agg + (size_t)(tid >> 4) * NN * CHW + (tid & 15);
    float sum = 0.f;
    for (int n = s + q; n < e; n += 8)
        sum += fmaxf(ac[(size_t)n * CHW], 0.f);   // ReLU fused
    atomicAdd(&pooled[g * H + tid], sum);
    if (q == 0 && tid == 0) gcnt[g] = (float)(e - s);
}

// ---------------------------------------------------------------- LSTM (single step, h0=c0=0) + output head, fused
__global__ __launch_bounds__(256) void k_lstm(const float* __restrict__ pooled,
                                              const float* __restrict__ gcnt,
                                              const float* __restrict__ W_ih,
                                              const float* __restrict__ b_ih,
                                              const float* __restrict__ b_hh,
                                              const float* __restrict__ W_out,
                                              const float* __restrict__ b_out,
                                              float* __restrict__ out) {
    __shared__ __align__(16) float p[H];
    __shared__ __align__(16) float hn[LH];
    int g = blockIdx.x, t = threadIdx.x;
    if (t < H) p[t] = pooled[g * H + t] / fmaxf(gcnt[g], 1.f);
    __syncthreads();

    // gate rows (torch order i,f,g,o): f unused (c0=0)
    float si = b_ih[t] + b_hh[t];
    float sg = b_ih[2 * LH + t] + b_hh[2 * LH + t];
    float so = b_ih[3 * LH + t] + b_hh[3 * LH + t];
    const float* wi = W_ih + (size_t)t * H;
    const float* wg = W_ih + (size_t)(2 * LH + t) * H;
    const float* wo = W_ih + (size_t)(3 * LH + t) * H;
    for (int k = 0; k < H; k += 4) {
        float4 pv = *reinterpret_cast<const float4*>(&p[k]);
        float4 a = *reinterpret_cast<const float4*>(wi + k);
        si += pv.x * a.x + pv.y * a.y + pv.z * a.z + pv.w * a.w;
        float4 b = *reinterpret_cast<const float4*>(wg + k);
        sg += pv.x * b.x + pv.y * b.y + pv.z * b.z + pv.w * b.w;
        float4 c = *reinterpret_cast<const float4*>(wo + k);
        so += pv.x * c.x + pv.y * c.y + pv.z * c.z + pv.w * c.w;
    }
    float ig = 1.f / (1.f + expf(-si));
    float cc = ig * tanhf(sg);
    float og = 1.f / (1.f + expf(-so));
    hn[t] = og * tanhf(cc);
    __syncthreads();

    if (t < OD) {
        float acc = b_out[t];
        const float* wr = W_out + (size_t)t * LH;
        for (int k = 0; k < LH; k += 4) {
            float4 hv = *reinterpret_cast<const float4*>(&hn[k]);
            float4 wv = *reinterpret_cast<const float4*>(wr + k);
            acc += hv.x * wv.x + hv.y * wv.y + hv.z * wv.z + hv.w * wv.w;
        }
        out[g * OD + t] = acc;
    }
}

// ----------------------------------------------------------------
extern "C" void kernel_launch(void* const* d_in, const int* in_sizes, int n_in,
                              void* d_out, int out_size, void* d_ws, size_t ws_size,
                              hipStream_t stream) {
    const float* x     = (const float*)d_in[0];
    const int*   ei    = (const int*)d_in[1];   // [2][NE]: rows then cols
    const int*   batch = (const int*)d_in[2];
    const float* Wg    = (const float*)d_in[3]; // [3][128][128]
    const float* bg    = (const float*)d_in[4]; // [3][128]
    const float* W_ih  = (const float*)d_in[5]; // [1024][128]
    const float* b_ih  = (const float*)d_in[7];
    const float* b_hh  = (const float*)d_in[8];
    const float* W_out = (const float*)d_in[9]; // [32][256]
    const float* b_out = (const float*)d_in[10];
    float* out = (float*)d_out;

    // workspace layout (~52 MB)
    float* ws = (float*)d_ws;
    unsigned short* tb = (unsigned short*)ws;        // NN*H bf16 (12.8 MB)
    float* buf1      = ws + (size_t)NN * H / 2;      // NN*H fp32 (agg, chunk-major)
    int*   part      = (int*)(buf1 + (size_t)NN * H); // NE ints (packed src<<8|dst&255)
    float* dinv      = (float*)(part + NE);          // NN
    float* pooled    = dinv + NN;                    // NG*H
    float* gcnt      = pooled + NG * H;              // NG
    int*   cnt       = (int*)(gcnt + NG);            // NN
    int*   rp        = cnt + NN;                     // NN
    int*   srcs      = rp + NN;                      // NE
    int*   bktCnt    = srcs + NE;                    // NBKT
    int*   bktBase   = bktCnt + NBKT;                // NBKT+1
    int*   bktCursor = bktBase + NBKT + 1;           // NBKT

    hipMemsetAsync(bktCnt, 0, NBKT * sizeof(int), stream);
    hipMemsetAsync(pooled, 0, (NG * H + NG) * sizeof(float), stream);

    // CSR build (by destination) — bucketed counting sort
    k_bhist<<<256, 256, 0, stream>>>(ei + NE, bktCnt);
    k_bscan<<<1, 256, 0, stream>>>(bktCnt, bktBase, bktCursor);
    k_part <<<NPARTB, 256, 0, stream>>>(ei, bktCursor, part);
    k_bfill<<<NBKT, 256, 0, stream>>>(bktBase, part, rp, cnt, dinv, srcs);

    const int gemmBlocks = (NN + 63) / 64;
    const int gathBlocks = ((NN + 63) / 64) * BCH;   // 782 * 4 = 3128

    // layer 0: x (row-major) -> tb -> buf1
    k_gemm<false, false><<<gemmBlocks, 256, 0, stream>>>(x, Wg, dinv, tb);
    k_gather<<<gathBlocks, 256, 0, stream>>>(rp, cnt, srcs, dinv, bg, tb, buf1);
    // layer 1: relu(buf1) -> tb -> buf1
    k_gemm<true, true><<<gemmBlocks, 256, 0, stream>>>(buf1, Wg + H * H, dinv, tb);
    k_gather<<<gathBlocks, 256, 0, stream>>>(rp, cnt, srcs, dinv, bg + H, tb, buf1);
    // layer 2: relu(buf1) -> tb -> buf1
    k_gemm<true, true><<<gemmBlocks, 256, 0, stream>>>(buf1, Wg + 2 * H * H, dinv, tb);
    k_gather<<<gathBlocks, 256, 0, stream>>>(rp, cnt, srcs, dinv, bg + 2 * H, tb, buf1);

    k_pool<<<NG * 8, 128, 0, stream>>>(batch, buf1, pooled, gcnt);
    k_lstm<<<NG, 256, 0, stream>>>(pooled, gcnt, W_ih, b_ih, b_hh, W_out, b_out, out);
}

// Round 12
// 292.948 us; speedup vs baseline: 3.2917x; 1.3849x over previous
//
#include <hip/hip_runtime.h>

// Problem constants (match reference setup_inputs)
constexpr int NN = 50000;     // nodes
constexpr int NE = 1600000;   // edges
constexpr int H  = 128;       // feature dim (F_IN == H)
constexpr int LH = 256;       // lstm hidden
constexpr int OD = 32;        // output dim
constexpr int NG = 64;        // graphs

// Bucketed CSR build: bucket = dst >> 8 (256 nodes per bucket)
constexpr int NBKT  = (NN + 255) / 256;           // 196
constexpr int PARTE = 4096;                       // edges per k_part block
constexpr int NPARTB = (NE + PARTE - 1) / PARTE;  // 391
static_assert(NBKT <= 256, "single-block scan assumes NBKT <= 256");

// agg layout: fp32 chunk-major, 8 chunks x 16 floats (pool/GEMM input).
constexpr int NCH = 8;
constexpr int CHW = 16;
// t' layout: bf16 chunk-major, 4 chunks x 32 bf16 (one 64B line per chunk-row).
constexpr int BCH = 4;
constexpr int BCW = 32;

// LDS-staged edge window per gather block (ints). 64 nodes * avg 32 ~ 2048.
constexpr int LSZ = 4608;

typedef __attribute__((ext_vector_type(8))) short short8v;  // 8 bf16 (4 VGPR)
typedef __attribute__((ext_vector_type(4))) float f32x4;    // MFMA acc

union BF8 { uint4 u; short8v s; };

__device__ __forceinline__ unsigned short f2bf(float x) {
    unsigned int u = __float_as_uint(x);
    u = (u + 0x7FFFu + ((u >> 16) & 1u)) >> 16;   // round-to-nearest-even
    return (unsigned short)u;
}

// ---------------------------------------------------------------- pass A: bucket histogram (LDS-aggregated)
__global__ __launch_bounds__(256) void k_bhist(const int* __restrict__ col,
                                               int* __restrict__ bktCnt) {
    __shared__ int h[NBKT];
    int t = threadIdx.x;
    if (t < NBKT) h[t] = 0;
    __syncthreads();
    for (int i = blockIdx.x * 256 + t; i < NE; i += gridDim.x * 256)
        atomicAdd(&h[col[i] >> 8], 1);
    __syncthreads();
    if (t < NBKT && h[t] > 0) atomicAdd(&bktCnt[t], h[t]);
}

// ---------------------------------------------------------------- pass B: scan bucket counts
__global__ __launch_bounds__(256) void k_bscan(const int* __restrict__ bktCnt,
                                               int* __restrict__ bktBase,
                                               int* __restrict__ bktCursor) {
    __shared__ int sh[256];
    int t = threadIdx.x;
    int v = (t < NBKT) ? bktCnt[t] : 0;
    sh[t] = v;
    __syncthreads();
    for (int off = 1; off < 256; off <<= 1) {
        int add = (t >= off) ? sh[t - off] : 0;
        __syncthreads();
        sh[t] += add;
        __syncthreads();
    }
    if (t < NBKT) {
        int excl = sh[t] - v;
        bktBase[t] = excl;
        bktCursor[t] = excl;
    }
    if (t == NBKT - 1) bktBase[NBKT] = sh[t];
}

// ---------------------------------------------------------------- pass C: partition edges, packed (src<<8 | dst&255)
__global__ __launch_bounds__(256) void k_part(const int* __restrict__ ei,
                                              int* __restrict__ bktCursor,
                                              int* __restrict__ part) {
    __shared__ int lcur[NBKT];
    __shared__ int lbase[NBKT];
    const int t = threadIdx.x;
    const int base = blockIdx.x * PARTE;
    int pk[16], bk[16];

    if (t < NBKT) lcur[t] = 0;
    __syncthreads();
#pragma unroll
    for (int j = 0; j < 16; ++j) {
        int e = base + j * 256 + t;
        if (e < NE) {
            int sr = ei[e];
            int ds = ei[NE + e];
            pk[j] = (sr << 8) | (ds & 255);
            bk[j] = ds >> 8;
            atomicAdd(&lcur[bk[j]], 1);
        }
    }
    __syncthreads();
    if (t < NBKT) {
        int c = lcur[t];
        lbase[t] = (c > 0) ? atomicAdd(&bktCursor[t], c) : 0;
        lcur[t] = 0;
    }
    __syncthreads();
#pragma unroll
    for (int j = 0; j < 16; ++j) {
        int e = base + j * 256 + t;
        if (e < NE) {
            int r = atomicAdd(&lcur[bk[j]], 1);
            part[lbase[bk[j]] + r] = pk[j];
        }
    }
}

// ---------------------------------------------------------------- pass D: per-bucket CSR finalize (all atomics in LDS)
__global__ __launch_bounds__(256) void k_bfill(const int* __restrict__ bktBase,
                                               const int* __restrict__ part,
                                               int* __restrict__ rp,
                                               int* __restrict__ cnt,
                                               float* __restrict__ dinv,
                                               int* __restrict__ srcs) {
    __shared__ int h[256];
    __shared__ int sc[256];
    __shared__ int cur[256];
    const int b = blockIdx.x, t = threadIdx.x;
    const int lo = bktBase[b], hi = bktBase[b + 1];

    h[t] = 0;
    __syncthreads();
    for (int i = lo + t; i < hi; i += 256)
        atomicAdd(&h[part[i] & 255], 1);
    __syncthreads();
    int v = h[t];
    sc[t] = v;
    __syncthreads();
    for (int off = 1; off < 256; off <<= 1) {
        int add = (t >= off) ? sc[t - off] : 0;
        __syncthreads();
        sc[t] += add;
        __syncthreads();
    }
    int excl = sc[t] - v;
    cur[t] = lo + excl;
    int node = b * 256 + t;
    if (node < NN) {
        rp[node] = lo + excl;
        cnt[node] = v;
        dinv[node] = rsqrtf((float)v + 1.0f);   // self-loop adds 1
    }
    __syncthreads();
    for (int i = lo + t; i < hi; i += 256) {
        int e = part[i];
        int pos = atomicAdd(&cur[e & 255], 1);
        srcs[pos] = e >> 8;
    }
}

// ---------------------------------------------------------------- GEMM t' = (relu?)(h) @ W * dinv[row], MFMA bf16
// W staged to LDS as pre-swizzled bf16 B-fragments. Wave = 16 rows x 128 cols
// = 8 col-tiles x 4 K-steps of mfma_f32_16x16x32_bf16 (fp32 accumulate).
// Layouts (m89-verified family): A row=lane&15, k=8*(lane>>4)+j;
// B col=lane&15, same k; D col=lane&15, row=(lane>>4)*4+reg.
template <bool RELU, bool CHIN>
__global__ __launch_bounds__(256) void k_gemm(const float* __restrict__ h,
                                              const float* __restrict__ W,
                                              const float* __restrict__ dinv,
                                              unsigned short* __restrict__ tb) {
    __shared__ uint4 lw[2048];   // [ct][ks][lane] -> 8 bf16 of B-fragment
    const int tid = threadIdx.x;

    // stage W (fp32 [128][128]) -> LDS bf16 fragments, once per block
    for (int e = tid; e < 2048; e += 256) {
        const int ct = e >> 8, ks = (e >> 6) & 3, l = e & 63;
        const int col = ct * 16 + (l & 15);
        const int kb  = ks * 32 + ((l >> 4) << 3);
        const float* wp = W + (size_t)kb * H + col;
        unsigned int p0 = (unsigned)f2bf(wp[0])     | ((unsigned)f2bf(wp[H])     << 16);
        unsigned int p1 = (unsigned)f2bf(wp[2 * H]) | ((unsigned)f2bf(wp[3 * H]) << 16);
        unsigned int p2 = (unsigned)f2bf(wp[4 * H]) | ((unsigned)f2bf(wp[5 * H]) << 16);
        unsigned int p3 = (unsigned)f2bf(wp[6 * H]) | ((unsigned)f2bf(wp[7 * H]) << 16);
        lw[e] = make_uint4(p0, p1, p2, p3);
    }
    __syncthreads();

    const int wave = tid >> 6, lane = tid & 63;
    const int rowbase = blockIdx.x * 64 + wave * 16;
    const int arow  = rowbase + (lane & 15);
    const int arowc = arow < NN ? arow : NN - 1;   // clamp loads
    const int koff  = (lane >> 4) << 3;

    f32x4 acc[8];
#pragma unroll
    for (int ct = 0; ct < 8; ++ct) acc[ct] = (f32x4){0.f, 0.f, 0.f, 0.f};

#pragma unroll
    for (int ks = 0; ks < 4; ++ks) {
        const int kb = ks * 32 + koff;
        float4 h0, h1;
        if (CHIN) {
            const float* base = h + ((size_t)(kb >> 4) * NN + arowc) * CHW + (kb & 8);
            h0 = *reinterpret_cast<const float4*>(base);
            h1 = *reinterpret_cast<const float4*>(base + 4);
        } else {
            const float* base = h + (size_t)arowc * H + kb;
            h0 = *reinterpret_cast<const float4*>(base);
            h1 = *reinterpret_cast<const float4*>(base + 4);
        }
        if (RELU) {
            h0.x = fmaxf(h0.x, 0.f); h0.y = fmaxf(h0.y, 0.f);
            h0.z = fmaxf(h0.z, 0.f); h0.w = fmaxf(h0.w, 0.f);
            h1.x = fmaxf(h1.x, 0.f); h1.y = fmaxf(h1.y, 0.f);
            h1.z = fmaxf(h1.z, 0.f); h1.w = fmaxf(h1.w, 0.f);
        }
        BF8 a;
        a.u = make_uint4(
            (unsigned)f2bf(h0.x) | ((unsigned)f2bf(h0.y) << 16),
            (unsigned)f2bf(h0.z) | ((unsigned)f2bf(h0.w) << 16),
            (unsigned)f2bf(h1.x) | ((unsigned)f2bf(h1.y) << 16),
            (unsigned)f2bf(h1.z) | ((unsigned)f2bf(h1.w) << 16));
#pragma unroll
        for (int ct = 0; ct < 8; ++ct) {
            BF8 b;
            b.u = lw[(ct * 4 + ks) * 64 + lane];
            acc[ct] = __builtin_amdgcn_mfma_f32_16x16x32_bf16(a.s, b.s, acc[ct], 0, 0, 0);
        }
    }

    // epilogue: D lane mapping col=lane&15, row=(lane>>4)*4+r
    const int colb = lane & 15;
    const int rrow = rowbase + ((lane >> 4) << 2);
#pragma unroll
    for (int r = 0; r < 4; ++r) {
        const int row = rrow + r;
        if (row < NN) {
            const float d = dinv[row];
#pragma unroll
            for (int ct = 0; ct < 8; ++ct) {
                const int feat = ct * 16 + colb;
                tb[((size_t)(feat >> 5) * NN + row) * BCW + (feat & 31)] =
                    f2bf(acc[ct][r] * d);
            }
        }
    }
}

// ---------------------------------------------------------------- gather (bf16 rows, LDS-staged indices):
// agg = bg + dinv[n] * (t'[n] + sum_e t'[src[e]]) ; t' bf16, accum fp32.
__global__ __launch_bounds__(256) void k_gather(const int* __restrict__ rp,
                                                const int* __restrict__ cnt,
                                                const int* __restrict__ srcs,
                                                const float* __restrict__ dinv,
                                                const float* __restrict__ bg,
                                                const unsigned short* __restrict__ tb,
                                                float* __restrict__ agg) {
    __shared__ int lsrcs[LSZ];
    const int tid  = threadIdx.x;
    const int wv   = tid >> 6;         // 0..3
    const int lane = tid & 63;
    const int slot = lane >> 2;        // node group 0..15
    const int l4   = lane & 3;         // uint4 index within 64B row
    const int c    = blockIdx.x & 3;   // bf16 chunk (-> XCDs {c, c+4})
    const int nb   = blockIdx.x >> 2;  // node block (64 nodes)
    const int n0   = nb * 64;
    const int n    = n0 + wv * 16 + slot;

    const int eLo = rp[n0];
    int nLast = n0 + 63; if (nLast >= NN) nLast = NN - 1;
    const int eHi = rp[nLast] + cnt[nLast];
    const bool staged = (eHi - eLo) <= LSZ;   // block-uniform

    if (staged) {
        for (int i = eLo + tid; i < eHi; i += 256)
            lsrcs[i - eLo] = srcs[i];
    }
    __syncthreads();

    if (n >= NN) return;

    const uint4* __restrict__ tb4 =
        reinterpret_cast<const uint4*>(tb) + (size_t)c * NN * 4;
    const float4 bg0 = *reinterpret_cast<const float4*>(bg + c * BCW + l4 * 8);
    const float4 bg1 = *reinterpret_cast<const float4*>(bg + c * BCW + l4 * 8 + 4);

    const int i0  = rp[n];
    const int end = i0 + cnt[n];
    float4 p = make_float4(0.f, 0.f, 0.f, 0.f);
    float4 q = make_float4(0.f, 0.f, 0.f, 0.f);

#define ACC8(v)                                                        \
    do {                                                               \
        p.x += __uint_as_float((v).x << 16);                           \
        p.y += __uint_as_float((v).x & 0xFFFF0000u);                   \
        p.z += __uint_as_float((v).y << 16);                           \
        p.w += __uint_as_float((v).y & 0xFFFF0000u);                   \
        q.x += __uint_as_float((v).z << 16);                           \
        q.y += __uint_as_float((v).z & 0xFFFF0000u);                   \
        q.z += __uint_as_float((v).w << 16);                           \
        q.w += __uint_as_float((v).w & 0xFFFF0000u);                   \
    } while (0)

    if (staged) {
        int i = i0;
        for (; i + 7 < end; i += 8) {
            int s0 = lsrcs[i     - eLo], s1 = lsrcs[i + 1 - eLo];
            int s2 = lsrcs[i + 2 - eLo], s3 = lsrcs[i + 3 - eLo];
            int s4 = lsrcs[i + 4 - eLo], s5 = lsrcs[i + 5 - eLo];
            int s6 = lsrcs[i + 6 - eLo], s7 = lsrcs[i + 7 - eLo];
            uint4 v0 = tb4[(size_t)s0 * 4 + l4];
            uint4 v1 = tb4[(size_t)s1 * 4 + l4];
            uint4 v2 = tb4[(size_t)s2 * 4 + l4];
            uint4 v3 = tb4[(size_t)s3 * 4 + l4];
            uint4 v4 = tb4[(size_t)s4 * 4 + l4];
            uint4 v5 = tb4[(size_t)s5 * 4 + l4];
            uint4 v6 = tb4[(size_t)s6 * 4 + l4];
            uint4 v7 = tb4[(size_t)s7 * 4 + l4];
            ACC8(v0); ACC8(v1); ACC8(v2); ACC8(v3);
            ACC8(v4); ACC8(v5); ACC8(v6); ACC8(v7);
        }
        for (; i < end; ++i) {
            uint4 v = tb4[(size_t)lsrcs[i - eLo] * 4 + l4];
            ACC8(v);
        }
    } else {
        int i = i0;
        for (; i + 3 < end; i += 4) {
            int s0 = srcs[i], s1 = srcs[i + 1], s2 = srcs[i + 2], s3 = srcs[i + 3];
            uint4 v0 = tb4[(size_t)s0 * 4 + l4];
            uint4 v1 = tb4[(size_t)s1 * 4 + l4];
            uint4 v2 = tb4[(size_t)s2 * 4 + l4];
            uint4 v3 = tb4[(size_t)s3 * 4 + l4];
            ACC8(v0); ACC8(v1); ACC8(v2); ACC8(v3);
        }
        for (; i < end; ++i) {
            uint4 v = tb4[(size_t)srcs[i] * 4 + l4];
            ACC8(v);
        }
    }

    uint4 sv = tb4[(size_t)n * 4 + l4];   // self-loop term
    ACC8(sv);
#undef ACC8

    const float d = dinv[n];
    float4 o0, o1;
    o0.x = fmaf(p.x, d, bg0.x); o0.y = fmaf(p.y, d, bg0.y);
    o0.z = fmaf(p.z, d, bg0.z); o0.w = fmaf(p.w, d, bg0.w);
    o1.x = fmaf(q.x, d, bg1.x); o1.y = fmaf(q.y, d, bg1.y);
    o1.z = fmaf(q.z, d, bg1.z); o1.w = fmaf(q.w, d, bg1.w);

    // agg fp32 chunk-major CHW=16: feature f = c*32 + l4*8 + j
    const int fc = 2 * c + (l4 >> 1);
    float* dst = agg + ((size_t)fc * NN + n) * CHW + (l4 & 1) * 8;
    *reinterpret_cast<float4*>(dst)     = o0;
    *reinterpret_cast<float4*>(dst + 4) = o1;
}

// ---------------------------------------------------------------- mean pool (batch sorted -> binary search bounds)
__device__ __forceinline__ int lower_bound_dev(const int* __restrict__ b, int v) {
    int lo = 0, hi = NN;
    while (lo < hi) {
        int m = (lo + hi) >> 1;
        if (b[m] < v) lo = m + 1; else hi = m;
    }
    return lo;
}

__global__ __launch_bounds__(128) void k_pool(const int* __restrict__ batch,
                                              const float* __restrict__ agg,  // fp32 chunk-major
                                              float* __restrict__ pooled,
                                              float* __restrict__ gcnt) {
    int g = blockIdx.x >> 3;   // 8 blocks per graph
    int q = blockIdx.x & 7;
    int tid = threadIdx.x;     // feature index f = tid
    int s = lower_bound_dev(batch, g);
    int e = lower_bound_dev(batch, g + 1);
    const float* __restrict__ ac = agg + (size_t)(tid >> 4) * NN * CHW + (tid & 15);
    float sum = 0.f;
    for (int n = s + q; n < e; n += 8)
        sum += fmaxf(ac[(size_t)n * CHW], 0.f);   // ReLU fused
    atomicAdd(&pooled[g * H + tid], sum);
    if (q == 0 && tid == 0) gcnt[g] = (float)(e - s);
}

// ---------------------------------------------------------------- LSTM (single step, h0=c0=0) + output head, fused
__global__ __launch_bounds__(256) void k_lstm(const float* __restrict__ pooled,
                                              const float* __restrict__ gcnt,
                                              const float* __restrict__ W_ih,
                                              const float* __restrict__ b_ih,
                                              const float* __restrict__ b_hh,
                                              const float* __restrict__ W_out,
                                              const float* __restrict__ b_out,
                                              float* __restrict__ out) {
    __shared__ __align__(16) float p[H];
    __shared__ __align__(16) float hn[LH];
    int g = blockIdx.x, t = threadIdx.x;
    if (t < H) p[t] = pooled[g * H + t] / fmaxf(gcnt[g], 1.f);
    __syncthreads();

    // gate rows (torch order i,f,g,o): f unused (c0=0)
    float si = b_ih[t] + b_hh[t];
    float sg = b_ih[2 * LH + t] + b_hh[2 * LH + t];
    float so = b_ih[3 * LH + t] + b_hh[3 * LH + t];
    const float* wi = W_ih + (size_t)t * H;
    const float* wg = W_ih + (size_t)(2 * LH + t) * H;
    const float* wo = W_ih + (size_t)(3 * LH + t) * H;
    for (int k = 0; k < H; k += 4) {
        float4 pv = *reinterpret_cast<const float4*>(&p[k]);
        float4 a = *reinterpret_cast<const float4*>(wi + k);
        si += pv.x * a.x + pv.y * a.y + pv.z * a.z + pv.w * a.w;
        float4 b = *reinterpret_cast<const float4*>(wg + k);
        sg += pv.x * b.x + pv.y * b.y + pv.z * b.z + pv.w * b.w;
        float4 c = *reinterpret_cast<const float4*>(wo + k);
        so += pv.x * c.x + pv.y * c.y + pv.z * c.z + pv.w * c.w;
    }
    float ig = 1.f / (1.f + expf(-si));
    float cc = ig * tanhf(sg);
    float og = 1.f / (1.f + expf(-so));
    hn[t] = og * tanhf(cc);
    __syncthreads();

    if (t < OD) {
        float acc = b_out[t];
        const float* wr = W_out + (size_t)t * LH;
        for (int k = 0; k < LH; k += 4) {
            float4 hv = *reinterpret_cast<const float4*>(&hn[k]);
            float4 wv = *reinterpret_cast<const float4*>(wr + k);
            acc += hv.x * wv.x + hv.y * wv.y + hv.z * wv.z + hv.w * wv.w;
        }
        out[g * OD + t] = acc;
    }
}

// ----------------------------------------------------------------
extern "C" void kernel_launch(void* const* d_in, const int* in_sizes, int n_in,
                              void* d_out, int out_size, void* d_ws, size_t ws_size,
                              hipStream_t stream) {
    const float* x     = (const float*)d_in[0];
    const int*   ei    = (const int*)d_in[1];   // [2][NE]: rows then cols
    const int*   batch = (const int*)d_in[2];
    const float* Wg    = (const float*)d_in[3]; // [3][128][128]
    const float* bg    = (const float*)d_in[4]; // [3][128]
    const float* W_ih  = (const float*)d_in[5]; // [1024][128]
    const float* b_ih  = (const float*)d_in[7];
    const float* b_hh  = (const float*)d_in[8];
    const float* W_out = (const float*)d_in[9]; // [32][256]
    const float* b_out = (const float*)d_in[10];
    float* out = (float*)d_out;

    // workspace layout (~52 MB)
    float* ws = (float*)d_ws;
    unsigned short* tb = (unsigned short*)ws;        // NN*H bf16 (12.8 MB)
    float* buf1      = ws + (size_t)NN * H / 2;      // NN*H fp32 (agg, chunk-major)
    int*   part      = (int*)(buf1 + (size_t)NN * H); // NE ints (packed src<<8|dst&255)
    float* dinv      = (float*)(part + NE);          // NN
    float* pooled    = dinv + NN;                    // NG*H
    float* gcnt      = pooled + NG * H;              // NG
    int*   cnt       = (int*)(gcnt + NG);            // NN
    int*   rp        = cnt + NN;                     // NN
    int*   srcs      = rp + NN;                      // NE
    int*   bktCnt    = srcs + NE;                    // NBKT
    int*   bktBase   = bktCnt + NBKT;                // NBKT+1
    int*   bktCursor = bktBase + NBKT + 1;           // NBKT

    hipMemsetAsync(bktCnt, 0, NBKT * sizeof(int), stream);
    hipMemsetAsync(pooled, 0, (NG * H + NG) * sizeof(float), stream);

    // CSR build (by destination) — bucketed counting sort
    k_bhist<<<256, 256, 0, stream>>>(ei + NE, bktCnt);
    k_bscan<<<1, 256, 0, stream>>>(bktCnt, bktBase, bktCursor);
    k_part <<<NPARTB, 256, 0, stream>>>(ei, bktCursor, part);
    k_bfill<<<NBKT, 256, 0, stream>>>(bktBase, part, rp, cnt, dinv, srcs);

    const int gemmBlocks = (NN + 63) / 64;
    const int gathBlocks = ((NN + 63) / 64) * BCH;   // 782 * 4 = 3128

    // layer 0: x (row-major) -> tb -> buf1
    k_gemm<false, false><<<gemmBlocks, 256, 0, stream>>>(x, Wg, dinv, tb);
    k_gather<<<gathBlocks, 256, 0, stream>>>(rp, cnt, srcs, dinv, bg, tb, buf1);
    // layer 1: relu(buf1) -> tb -> buf1
    k_gemm<true, true><<<gemmBlocks, 256, 0, stream>>>(buf1, Wg + H * H, dinv, tb);
    k_gather<<<gathBlocks, 256, 0, stream>>>(rp, cnt, srcs, dinv, bg + H, tb, buf1);
    // layer 2: relu(buf1) -> tb -> buf1
    k_gemm<true, true><<<gemmBlocks, 256, 0, stream>>>(buf1, Wg + 2 * H * H, dinv, tb);
    k_gather<<<gathBlocks, 256, 0, stream>>>(rp, cnt, srcs, dinv, bg + 2 * H, tb, buf1);

    k_pool<<<NG * 8, 128, 0, stream>>>(batch, buf1, pooled, gcnt);
    k_lstm<<<NG, 256, 0, stream>>>(pooled, gcnt, W_ih, b_ih, b_hh, W_out, b_out, out);
}

// Round 13
// 280.117 us; speedup vs baseline: 3.4425x; 1.0458x over previous
//
#include <hip/hip_runtime.h>

// Problem constants (match reference setup_inputs)
constexpr int NN = 50000;     // nodes
constexpr int NE = 1600000;   // edges
constexpr int H  = 128;       // feature dim (F_IN == H)
constexpr int LH = 256;       // lstm hidden
constexpr int OD = 32;        // output dim
constexpr int NG = 64;        // graphs

// Bucketed CSR build: bucket = dst >> 8 (256 nodes per bucket)
constexpr int NBKT  = (NN + 255) / 256;           // 196
constexpr int PARTE = 4096;                       // edges per k_part block
constexpr int NPARTB = (NE + PARTE - 1) / PARTE;  // 391
static_assert(NBKT <= 256, "single-block scan assumes NBKT <= 256");

// t'/agg layout: bf16 chunk-major, 4 chunks x 32 bf16 (64B line per chunk-row).
// Gather: chunk = blockIdx&3 -> XCD affinity; per-XCD set = NN*64B = 3.2MB < 4MB.
constexpr int BCH = 4;
constexpr int BCW = 32;

// LDS-staged edge window per gather block (ints). 64 nodes * avg 32 ~ 2048.
constexpr int LSZ = 4608;

typedef __attribute__((ext_vector_type(8))) short short8v;  // 8 bf16 (4 VGPR)
typedef __attribute__((ext_vector_type(4))) float f32x4;    // MFMA acc

union BF8 { uint4 u; short8v s; };

__device__ __forceinline__ unsigned short f2bf(float x) {
    unsigned int u = __float_as_uint(x);
    u = (u + 0x7FFFu + ((u >> 16) & 1u)) >> 16;   // round-to-nearest-even
    return (unsigned short)u;
}

// ---------------------------------------------------------------- pass A: bucket histogram (LDS-aggregated)
__global__ __launch_bounds__(256) void k_bhist(const int* __restrict__ col,
                                               int* __restrict__ bktCnt) {
    __shared__ int h[NBKT];
    int t = threadIdx.x;
    if (t < NBKT) h[t] = 0;
    __syncthreads();
    for (int i = blockIdx.x * 256 + t; i < NE; i += gridDim.x * 256)
        atomicAdd(&h[col[i] >> 8], 1);
    __syncthreads();
    if (t < NBKT && h[t] > 0) atomicAdd(&bktCnt[t], h[t]);
}

// ---------------------------------------------------------------- pass B: scan bucket counts
__global__ __launch_bounds__(256) void k_bscan(const int* __restrict__ bktCnt,
                                               int* __restrict__ bktBase,
                                               int* __restrict__ bktCursor) {
    __shared__ int sh[256];
    int t = threadIdx.x;
    int v = (t < NBKT) ? bktCnt[t] : 0;
    sh[t] = v;
    __syncthreads();
    for (int off = 1; off < 256; off <<= 1) {
        int add = (t >= off) ? sh[t - off] : 0;
        __syncthreads();
        sh[t] += add;
        __syncthreads();
    }
    if (t < NBKT) {
        int excl = sh[t] - v;
        bktBase[t] = excl;
        bktCursor[t] = excl;
    }
    if (t == NBKT - 1) bktBase[NBKT] = sh[t];
}

// ---------------------------------------------------------------- pass C: partition edges, packed (src<<8 | dst&255)
__global__ __launch_bounds__(256) void k_part(const int* __restrict__ ei,
                                              int* __restrict__ bktCursor,
                                              int* __restrict__ part) {
    __shared__ int lcur[NBKT];
    __shared__ int lbase[NBKT];
    const int t = threadIdx.x;
    const int base = blockIdx.x * PARTE;
    int pk[16], bk[16];

    if (t < NBKT) lcur[t] = 0;
    __syncthreads();
#pragma unroll
    for (int j = 0; j < 16; ++j) {
        int e = base + j * 256 + t;
        if (e < NE) {
            int sr = ei[e];
            int ds = ei[NE + e];
            pk[j] = (sr << 8) | (ds & 255);
            bk[j] = ds >> 8;
            atomicAdd(&lcur[bk[j]], 1);
        }
    }
    __syncthreads();
    if (t < NBKT) {
        int c = lcur[t];
        lbase[t] = (c > 0) ? atomicAdd(&bktCursor[t], c) : 0;
        lcur[t] = 0;
    }
    __syncthreads();
#pragma unroll
    for (int j = 0; j < 16; ++j) {
        int e = base + j * 256 + t;
        if (e < NE) {
            int r = atomicAdd(&lcur[bk[j]], 1);
            part[lbase[bk[j]] + r] = pk[j];
        }
    }
}

// ---------------------------------------------------------------- pass D: per-bucket CSR finalize (all atomics in LDS)
__global__ __launch_bounds__(256) void k_bfill(const int* __restrict__ bktBase,
                                               const int* __restrict__ part,
                                               int* __restrict__ rp,
                                               int* __restrict__ cnt,
                                               float* __restrict__ dinv,
                                               int* __restrict__ srcs) {
    __shared__ int h[256];
    __shared__ int sc[256];
    __shared__ int cur[256];
    const int b = blockIdx.x, t = threadIdx.x;
    const int lo = bktBase[b], hi = bktBase[b + 1];

    h[t] = 0;
    __syncthreads();
    for (int i = lo + t; i < hi; i += 256)
        atomicAdd(&h[part[i] & 255], 1);
    __syncthreads();
    int v = h[t];
    sc[t] = v;
    __syncthreads();
    for (int off = 1; off < 256; off <<= 1) {
        int add = (t >= off) ? sc[t - off] : 0;
        __syncthreads();
        sc[t] += add;
        __syncthreads();
    }
    int excl = sc[t] - v;
    cur[t] = lo + excl;
    int node = b * 256 + t;
    if (node < NN) {
        rp[node] = lo + excl;
        cnt[node] = v;
        dinv[node] = rsqrtf((float)v + 1.0f);   // self-loop adds 1
    }
    __syncthreads();
    for (int i = lo + t; i < hi; i += 256) {
        int e = part[i];
        int pos = atomicAdd(&cur[e & 255], 1);
        srcs[pos] = e >> 8;
    }
}

// ---------------------------------------------------------------- GEMM t' = (relu?)(h) @ W * dinv[row], MFMA bf16
// Input: fp32 row-major (layer 0) or bf16 chunk-major [4][NN][32] (layers 1,2).
// Output: bf16 chunk-major tb. W staged to LDS as bf16 B-fragments.
template <bool RELU, bool CHIN>
__global__ __launch_bounds__(256) void k_gemm(const float* __restrict__ hf,
                                              const unsigned short* __restrict__ hb,
                                              const float* __restrict__ W,
                                              const float* __restrict__ dinv,
                                              unsigned short* __restrict__ tb) {
    __shared__ uint4 lw[2048];   // [ct][ks][lane] -> 8 bf16 of B-fragment
    const int tid = threadIdx.x;

    // stage W (fp32 [128][128]) -> LDS bf16 fragments, once per block
    for (int e = tid; e < 2048; e += 256) {
        const int ct = e >> 8, ks = (e >> 6) & 3, l = e & 63;
        const int col = ct * 16 + (l & 15);
        const int kb  = ks * 32 + ((l >> 4) << 3);
        const float* wp = W + (size_t)kb * H + col;
        unsigned int p0 = (unsigned)f2bf(wp[0])     | ((unsigned)f2bf(wp[H])     << 16);
        unsigned int p1 = (unsigned)f2bf(wp[2 * H]) | ((unsigned)f2bf(wp[3 * H]) << 16);
        unsigned int p2 = (unsigned)f2bf(wp[4 * H]) | ((unsigned)f2bf(wp[5 * H]) << 16);
        unsigned int p3 = (unsigned)f2bf(wp[6 * H]) | ((unsigned)f2bf(wp[7 * H]) << 16);
        lw[e] = make_uint4(p0, p1, p2, p3);
    }
    __syncthreads();

    const int wave = tid >> 6, lane = tid & 63;
    const int rowbase = blockIdx.x * 64 + wave * 16;
    const int arow  = rowbase + (lane & 15);
    const int arowc = arow < NN ? arow : NN - 1;   // clamp loads
    const int koff  = (lane >> 4) << 3;

    f32x4 acc[8];
#pragma unroll
    for (int ct = 0; ct < 8; ++ct) acc[ct] = (f32x4){0.f, 0.f, 0.f, 0.f};

#pragma unroll
    for (int ks = 0; ks < 4; ++ks) {
        BF8 a;
        if (CHIN) {
            // bf16 chunk-major: feats ks*32+koff..+7 = one uint4
            a.u = *reinterpret_cast<const uint4*>(
                hb + ((size_t)ks * NN + arowc) * BCW + koff);
            if (RELU) {
                unsigned int m;
                m = ((a.u.x >> 15) & 0x00010001u) * 0xFFFFu; a.u.x &= ~m;
                m = ((a.u.y >> 15) & 0x00010001u) * 0xFFFFu; a.u.y &= ~m;
                m = ((a.u.z >> 15) & 0x00010001u) * 0xFFFFu; a.u.z &= ~m;
                m = ((a.u.w >> 15) & 0x00010001u) * 0xFFFFu; a.u.w &= ~m;
            }
        } else {
            const int kb = ks * 32 + koff;
            const float* base = hf + (size_t)arowc * H + kb;
            float4 h0 = *reinterpret_cast<const float4*>(base);
            float4 h1 = *reinterpret_cast<const float4*>(base + 4);
            if (RELU) {
                h0.x = fmaxf(h0.x, 0.f); h0.y = fmaxf(h0.y, 0.f);
                h0.z = fmaxf(h0.z, 0.f); h0.w = fmaxf(h0.w, 0.f);
                h1.x = fmaxf(h1.x, 0.f); h1.y = fmaxf(h1.y, 0.f);
                h1.z = fmaxf(h1.z, 0.f); h1.w = fmaxf(h1.w, 0.f);
            }
            a.u = make_uint4(
                (unsigned)f2bf(h0.x) | ((unsigned)f2bf(h0.y) << 16),
                (unsigned)f2bf(h0.z) | ((unsigned)f2bf(h0.w) << 16),
                (unsigned)f2bf(h1.x) | ((unsigned)f2bf(h1.y) << 16),
                (unsigned)f2bf(h1.z) | ((unsigned)f2bf(h1.w) << 16));
        }
#pragma unroll
        for (int ct = 0; ct < 8; ++ct) {
            BF8 b;
            b.u = lw[(ct * 4 + ks) * 64 + lane];
            acc[ct] = __builtin_amdgcn_mfma_f32_16x16x32_bf16(a.s, b.s, acc[ct], 0, 0, 0);
        }
    }

    // epilogue: D lane mapping col=lane&15, row=(lane>>4)*4+r
    const int colb = lane & 15;
    const int rrow = rowbase + ((lane >> 4) << 2);
#pragma unroll
    for (int r = 0; r < 4; ++r) {
        const int row = rrow + r;
        if (row < NN) {
            const float d = dinv[row];
#pragma unroll
            for (int ct = 0; ct < 8; ++ct) {
                const int feat = ct * 16 + colb;
                tb[((size_t)(feat >> 5) * NN + row) * BCW + (feat & 31)] =
                    f2bf(acc[ct][r] * d);
            }
        }
    }
}

// ---------------------------------------------------------------- gather (bf16 rows, LDS-staged indices)
// o = bg + dinv[n] * (t'[n] + sum_e t'[src[e]]) ; t' bf16, accum fp32.
// POOL=0: write o as bf16 to aggb (same layout as tb).
// POOL=1 (layer 3): fuse mean-pool: relu(o) accumulated per-graph via LDS,
//                   then few global atomics into pooled. No agg write.
template <int POOL>
__global__ __launch_bounds__(256) void k_gather(const int* __restrict__ rp,
                                                const int* __restrict__ cnt,
                                                const int* __restrict__ srcs,
                                                const float* __restrict__ dinv,
                                                const float* __restrict__ bg,
                                                const unsigned short* __restrict__ tb,
                                                unsigned short* __restrict__ aggb,
                                                const int* __restrict__ batch,
                                                float* __restrict__ pooled) {
    __shared__ int lsrcs[LSZ];
    const int tid  = threadIdx.x;
    const int wv   = tid >> 6;         // 0..3
    const int lane = tid & 63;
    const int slot = lane >> 2;        // node group 0..15
    const int l4   = lane & 3;         // uint4 index within 64B row
    const int c    = blockIdx.x & 3;   // bf16 chunk (XCD affinity)
    const int nb   = blockIdx.x >> 2;  // node block (64 nodes)
    const int n0   = nb * 64;
    const int n    = n0 + wv * 16 + slot;

    const int eLo = rp[n0];
    int nLast = n0 + 63; if (nLast >= NN) nLast = NN - 1;
    const int eHi = rp[nLast] + cnt[nLast];
    const bool staged = (eHi - eLo) <= LSZ;   // block-uniform

    if (staged) {
        for (int i = eLo + tid; i < eHi; i += 256)
            lsrcs[i - eLo] = srcs[i];
    }

#if 1
    __shared__ float psum[4][32];   // POOL accumulator (unused if POOL==0)
#endif
    int g0 = 0;
    bool bigspan = false;
    if (POOL) {
        if (tid < 128) psum[tid >> 5][tid & 31] = 0.f;
        g0 = batch[n0];
        bigspan = (batch[nLast] - g0) > 3;   // ~impossible; safe fallback
    }
    __syncthreads();

    if (n >= NN) return;

    const uint4* __restrict__ tb4 =
        reinterpret_cast<const uint4*>(tb) + (size_t)c * NN * 4;
    const float4 bg0 = *reinterpret_cast<const float4*>(bg + c * BCW + l4 * 8);
    const float4 bg1 = *reinterpret_cast<const float4*>(bg + c * BCW + l4 * 8 + 4);

    const int i0  = rp[n];
    const int end = i0 + cnt[n];
    float4 p = make_float4(0.f, 0.f, 0.f, 0.f);
    float4 q = make_float4(0.f, 0.f, 0.f, 0.f);

#define ACC8(v)                                                        \
    do {                                                               \
        p.x += __uint_as_float((v).x << 16);                           \
        p.y += __uint_as_float((v).x & 0xFFFF0000u);                   \
        p.z += __uint_as_float((v).y << 16);                           \
        p.w += __uint_as_float((v).y & 0xFFFF0000u);                   \
        q.x += __uint_as_float((v).z << 16);                           \
        q.y += __uint_as_float((v).z & 0xFFFF0000u);                   \
        q.z += __uint_as_float((v).w << 16);                           \
        q.w += __uint_as_float((v).w & 0xFFFF0000u);                   \
    } while (0)

    if (staged) {
        int i = i0;
        for (; i + 7 < end; i += 8) {
            int s0 = lsrcs[i     - eLo], s1 = lsrcs[i + 1 - eLo];
            int s2 = lsrcs[i + 2 - eLo], s3 = lsrcs[i + 3 - eLo];
            int s4 = lsrcs[i + 4 - eLo], s5 = lsrcs[i + 5 - eLo];
            int s6 = lsrcs[i + 6 - eLo], s7 = lsrcs[i + 7 - eLo];
            uint4 v0 = tb4[(size_t)s0 * 4 + l4];
            uint4 v1 = tb4[(size_t)s1 * 4 + l4];
            uint4 v2 = tb4[(size_t)s2 * 4 + l4];
            uint4 v3 = tb4[(size_t)s3 * 4 + l4];
            uint4 v4 = tb4[(size_t)s4 * 4 + l4];
            uint4 v5 = tb4[(size_t)s5 * 4 + l4];
            uint4 v6 = tb4[(size_t)s6 * 4 + l4];
            uint4 v7 = tb4[(size_t)s7 * 4 + l4];
            ACC8(v0); ACC8(v1); ACC8(v2); ACC8(v3);
            ACC8(v4); ACC8(v5); ACC8(v6); ACC8(v7);
        }
        for (; i < end; ++i) {
            uint4 v = tb4[(size_t)lsrcs[i - eLo] * 4 + l4];
            ACC8(v);
        }
    } else {
        int i = i0;
        for (; i + 3 < end; i += 4) {
            int s0 = srcs[i], s1 = srcs[i + 1], s2 = srcs[i + 2], s3 = srcs[i + 3];
            uint4 v0 = tb4[(size_t)s0 * 4 + l4];
            uint4 v1 = tb4[(size_t)s1 * 4 + l4];
            uint4 v2 = tb4[(size_t)s2 * 4 + l4];
            uint4 v3 = tb4[(size_t)s3 * 4 + l4];
            ACC8(v0); ACC8(v1); ACC8(v2); ACC8(v3);
        }
        for (; i < end; ++i) {
            uint4 v = tb4[(size_t)srcs[i] * 4 + l4];
            ACC8(v);
        }
    }

    uint4 sv = tb4[(size_t)n * 4 + l4];   // self-loop term
    ACC8(sv);
#undef ACC8

    const float d = dinv[n];
    float4 o0, o1;
    o0.x = fmaf(p.x, d, bg0.x); o0.y = fmaf(p.y, d, bg0.y);
    o0.z = fmaf(p.z, d, bg0.z); o0.w = fmaf(p.w, d, bg0.w);
    o1.x = fmaf(q.x, d, bg1.x); o1.y = fmaf(q.y, d, bg1.y);
    o1.z = fmaf(q.z, d, bg1.z); o1.w = fmaf(q.w, d, bg1.w);

    if (POOL == 0) {
        uint4 u;
        u.x = (unsigned)f2bf(o0.x) | ((unsigned)f2bf(o0.y) << 16);
        u.y = (unsigned)f2bf(o0.z) | ((unsigned)f2bf(o0.w) << 16);
        u.z = (unsigned)f2bf(o1.x) | ((unsigned)f2bf(o1.y) << 16);
        u.w = (unsigned)f2bf(o1.z) | ((unsigned)f2bf(o1.w) << 16);
        *reinterpret_cast<uint4*>(aggb + ((size_t)c * NN + n) * BCW + l4 * 8) = u;
    } else {
        // relu + pool
        o0.x = fmaxf(o0.x, 0.f); o0.y = fmaxf(o0.y, 0.f);
        o0.z = fmaxf(o0.z, 0.f); o0.w = fmaxf(o0.w, 0.f);
        o1.x = fmaxf(o1.x, 0.f); o1.y = fmaxf(o1.y, 0.f);
        o1.z = fmaxf(o1.z, 0.f); o1.w = fmaxf(o1.w, 0.f);
        if (bigspan) {
            float* dst = pooled + (size_t)batch[n] * H + c * BCW + l4 * 8;
            atomicAdd(dst + 0, o0.x); atomicAdd(dst + 1, o0.y);
            atomicAdd(dst + 2, o0.z); atomicAdd(dst + 3, o0.w);
            atomicAdd(dst + 4, o1.x); atomicAdd(dst + 5, o1.y);
            atomicAdd(dst + 6, o1.z); atomicAdd(dst + 7, o1.w);
        } else {
            const int gi = batch[n] - g0;
            float* ps = &psum[gi][l4 * 8];
            atomicAdd(ps + 0, o0.x); atomicAdd(ps + 1, o0.y);
            atomicAdd(ps + 2, o0.z); atomicAdd(ps + 3, o0.w);
            atomicAdd(ps + 4, o1.x); atomicAdd(ps + 5, o1.y);
            atomicAdd(ps + 6, o1.z); atomicAdd(ps + 7, o1.w);
            __syncthreads();
            if (tid < 64) {
#pragma unroll
                for (int k = 0; k < 2; ++k) {
                    int idx = tid + k * 64;        // 0..127
                    int gi2 = idx >> 5, f = idx & 31;
                    float v = psum[gi2][f];
                    if (v != 0.f)
                        atomicAdd(&pooled[(size_t)(g0 + gi2) * H + c * BCW + f], v);
                }
            }
        }
    }
}

// ---------------------------------------------------------------- helpers
__device__ __forceinline__ int lower_bound_dev(const int* __restrict__ b, int v) {
    int lo = 0, hi = NN;
    while (lo < hi) {
        int m = (lo + hi) >> 1;
        if (b[m] < v) lo = m + 1; else hi = m;
    }
    return lo;
}

// ---------------------------------------------------------------- LSTM (single step, h0=c0=0) + output head, fused
__global__ __launch_bounds__(256) void k_lstm(const float* __restrict__ pooled,
                                              const int* __restrict__ batch,
                                              const float* __restrict__ W_ih,
                                              const float* __restrict__ b_ih,
                                              const float* __restrict__ b_hh,
                                              const float* __restrict__ W_out,
                                              const float* __restrict__ b_out,
                                              float* __restrict__ out) {
    __shared__ __align__(16) float p[H];
    __shared__ __align__(16) float hn[LH];
    int g = blockIdx.x, t = threadIdx.x;
    if (t < H) {
        int s = lower_bound_dev(batch, g);
        int e = lower_bound_dev(batch, g + 1);
        p[t] = pooled[g * H + t] / fmaxf((float)(e - s), 1.f);
    }
    __syncthreads();

    // gate rows (torch order i,f,g,o): f unused (c0=0)
    float si = b_ih[t] + b_hh[t];
    float sg = b_ih[2 * LH + t] + b_hh[2 * LH + t];
    float so = b_ih[3 * LH + t] + b_hh[3 * LH + t];
    const float* wi = W_ih + (size_t)t * H;
    const float* wg = W_ih + (size_t)(2 * LH + t) * H;
    const float* wo = W_ih + (size_t)(3 * LH + t) * H;
    for (int k = 0; k < H; k += 4) {
        float4 pv = *reinterpret_cast<const float4*>(&p[k]);
        float4 a = *reinterpret_cast<const float4*>(wi + k);
        si += pv.x * a.x + pv.y * a.y + pv.z * a.z + pv.w * a.w;
        float4 b = *reinterpret_cast<const float4*>(wg + k);
        sg += pv.x * b.x + pv.y * b.y + pv.z * b.z + pv.w * b.w;
        float4 c = *reinterpret_cast<const float4*>(wo + k);
        so += pv.x * c.x + pv.y * c.y + pv.z * c.z + pv.w * c.w;
    }
    float ig = 1.f / (1.f + expf(-si));
    float cc = ig * tanhf(sg);
    float og = 1.f / (1.f + expf(-so));
    hn[t] = og * tanhf(cc);
    __syncthreads();

    if (t < OD) {
        float acc = b_out[t];
        const float* wr = W_out + (size_t)t * LH;
        for (int k = 0; k < LH; k += 4) {
            float4 hv = *reinterpret_cast<const float4*>(&hn[k]);
            float4 wv = *reinterpret_cast<const float4*>(wr + k);
            acc += hv.x * wv.x + hv.y * wv.y + hv.z * wv.z + hv.w * wv.w;
        }
        out[g * OD + t] = acc;
    }
}

// ----------------------------------------------------------------
extern "C" void kernel_launch(void* const* d_in, const int* in_sizes, int n_in,
                              void* d_out, int out_size, void* d_ws, size_t ws_size,
                              hipStream_t stream) {
    const float* x     = (const float*)d_in[0];
    const int*   ei    = (const int*)d_in[1];   // [2][NE]: rows then cols
    const int*   batch = (const int*)d_in[2];
    const float* Wg    = (const float*)d_in[3]; // [3][128][128]
    const float* bg    = (const float*)d_in[4]; // [3][128]
    const float* W_ih  = (const float*)d_in[5]; // [1024][128]
    const float* b_ih  = (const float*)d_in[7];
    const float* b_hh  = (const float*)d_in[8];
    const float* W_out = (const float*)d_in[9]; // [32][256]
    const float* b_out = (const float*)d_in[10];
    float* out = (float*)d_out;

    // workspace layout (~39 MB)
    unsigned short* tb   = (unsigned short*)d_ws;     // NN*H bf16 (12.8 MB)
    unsigned short* aggb = tb + (size_t)NN * H;       // NN*H bf16 (12.8 MB)
    int*   part      = (int*)(aggb + (size_t)NN * H); // NE ints (packed)
    float* dinv      = (float*)(part + NE);           // NN
    float* pooled    = dinv + NN;                     // NG*H
    int*   cnt       = (int*)(pooled + NG * H);       // NN
    int*   rp        = cnt + NN;                      // NN
    int*   srcs      = rp + NN;                       // NE
    int*   bktCnt    = srcs + NE;                     // NBKT
    int*   bktBase   = bktCnt + NBKT;                 // NBKT+1
    int*   bktCursor = bktBase + NBKT + 1;            // NBKT

    hipMemsetAsync(bktCnt, 0, NBKT * sizeof(int), stream);
    hipMemsetAsync(pooled, 0, NG * H * sizeof(float), stream);

    // CSR build (by destination) — bucketed counting sort
    k_bhist<<<256, 256, 0, stream>>>(ei + NE, bktCnt);
    k_bscan<<<1, 256, 0, stream>>>(bktCnt, bktBase, bktCursor);
    k_part <<<NPARTB, 256, 0, stream>>>(ei, bktCursor, part);
    k_bfill<<<NBKT, 256, 0, stream>>>(bktBase, part, rp, cnt, dinv, srcs);

    const int gemmBlocks = (NN + 63) / 64;
    const int gathBlocks = ((NN + 63) / 64) * BCH;   // 782 * 4 = 3128

    // layer 0: x (fp32 row-major) -> tb -> aggb
    k_gemm<false, false><<<gemmBlocks, 256, 0, stream>>>(x, nullptr, Wg, dinv, tb);
    k_gather<0><<<gathBlocks, 256, 0, stream>>>(rp, cnt, srcs, dinv, bg, tb, aggb, batch, pooled);
    // layer 1: relu(aggb) -> tb -> aggb
    k_gemm<true, true><<<gemmBlocks, 256, 0, stream>>>(nullptr, aggb, Wg + H * H, dinv, tb);
    k_gather<0><<<gathBlocks, 256, 0, stream>>>(rp, cnt, srcs, dinv, bg + H, tb, aggb, batch, pooled);
    // layer 2: relu(aggb) -> tb -> pooled (pool fused)
    k_gemm<true, true><<<gemmBlocks, 256, 0, stream>>>(nullptr, aggb, Wg + 2 * H * H, dinv, tb);
    k_gather<1><<<gathBlocks, 256, 0, stream>>>(rp, cnt, srcs, dinv, bg + 2 * H, tb, nullptr, batch, pooled);

    k_lstm<<<NG, 256, 0, stream>>>(pooled, batch, W_ih, b_ih, b_hh, W_out, b_out, out);
}

// Round 14
// 261.379 us; speedup vs baseline: 3.6893x; 1.0717x over previous
//
#include <hip/hip_runtime.h>

// Problem constants (match reference setup_inputs)
constexpr int NN = 50000;     // nodes
constexpr int NE = 1600000;   // edges
constexpr int H  = 128;       // feature dim (F_IN == H)
constexpr int LH = 256;       // lstm hidden
constexpr int OD = 32;        // output dim
constexpr int NG = 64;        // graphs

// Bucketed CSR build: bucket = dst >> 8 (256 nodes per bucket)
constexpr int NBKT  = (NN + 255) / 256;           // 196
constexpr int PARTE = 4096;                       // edges per k_part block
constexpr int NPARTB = (NE + PARTE - 1) / PARTE;  // 391
static_assert(NBKT <= 256, "single-block scan assumes NBKT <= 256");

// t'/agg layout: bf16 chunk-major, 4 chunks x 32 bf16 (64B line per chunk-row).
constexpr int BCH = 4;
constexpr int BCW = 32;

// LDS-staged edge window per gather block (ints). 64 nodes * avg 32 ~ 2048.
constexpr int LSZ = 4608;

typedef __attribute__((ext_vector_type(8))) short short8v;  // 8 bf16 (4 VGPR)
typedef __attribute__((ext_vector_type(4))) float f32x4;    // MFMA acc

union BF8 { uint4 u; short8v s; };

__device__ __forceinline__ unsigned short f2bf(float x) {
    unsigned int u = __float_as_uint(x);
    u = (u + 0x7FFFu + ((u >> 16) & 1u)) >> 16;   // round-to-nearest-even
    return (unsigned short)u;
}

// ---------------------------------------------------------------- pass A: bucket histogram (LDS-aggregated)
__global__ __launch_bounds__(256) void k_bhist(const int* __restrict__ col,
                                               int* __restrict__ bktCnt) {
    __shared__ int h[NBKT];
    int t = threadIdx.x;
    if (t < NBKT) h[t] = 0;
    __syncthreads();
    for (int i = blockIdx.x * 256 + t; i < NE; i += gridDim.x * 256)
        atomicAdd(&h[col[i] >> 8], 1);
    __syncthreads();
    if (t < NBKT && h[t] > 0) atomicAdd(&bktCnt[t], h[t]);
}

// ---------------------------------------------------------------- pass B: scan bucket counts
__global__ __launch_bounds__(256) void k_bscan(const int* __restrict__ bktCnt,
                                               int* __restrict__ bktBase,
                                               int* __restrict__ bktCursor) {
    __shared__ int sh[256];
    int t = threadIdx.x;
    int v = (t < NBKT) ? bktCnt[t] : 0;
    sh[t] = v;
    __syncthreads();
    for (int off = 1; off < 256; off <<= 1) {
        int add = (t >= off) ? sh[t - off] : 0;
        __syncthreads();
        sh[t] += add;
        __syncthreads();
    }
    if (t < NBKT) {
        int excl = sh[t] - v;
        bktBase[t] = excl;
        bktCursor[t] = excl;
    }
    if (t == NBKT - 1) bktBase[NBKT] = sh[t];
}

// ---------------------------------------------------------------- pass C: partition edges, packed (src<<8 | dst&255)
__global__ __launch_bounds__(256) void k_part(const int* __restrict__ ei,
                                              int* __restrict__ bktCursor,
                                              int* __restrict__ part) {
    __shared__ int lcur[NBKT];
    __shared__ int lbase[NBKT];
    const int t = threadIdx.x;
    const int base = blockIdx.x * PARTE;
    int pk[16], bk[16];

    if (t < NBKT) lcur[t] = 0;
    __syncthreads();
#pragma unroll
    for (int j = 0; j < 16; ++j) {
        int e = base + j * 256 + t;
        if (e < NE) {
            int sr = ei[e];
            int ds = ei[NE + e];
            pk[j] = (sr << 8) | (ds & 255);
            bk[j] = ds >> 8;
            atomicAdd(&lcur[bk[j]], 1);
        }
    }
    __syncthreads();
    if (t < NBKT) {
        int c = lcur[t];
        lbase[t] = (c > 0) ? atomicAdd(&bktCursor[t], c) : 0;
        lcur[t] = 0;
    }
    __syncthreads();
#pragma unroll
    for (int j = 0; j < 16; ++j) {
        int e = base + j * 256 + t;
        if (e < NE) {
            int r = atomicAdd(&lcur[bk[j]], 1);
            part[lbase[bk[j]] + r] = pk[j];
        }
    }
}

// ---------------------------------------------------------------- pass D: per-bucket CSR finalize (all atomics in LDS)
__global__ __launch_bounds__(256) void k_bfill(const int* __restrict__ bktBase,
                                               const int* __restrict__ part,
                                               int* __restrict__ rp,
                                               int* __restrict__ cnt,
                                               float* __restrict__ dinv,
                                               int* __restrict__ srcs) {
    __shared__ int h[256];
    __shared__ int sc[256];
    __shared__ int cur[256];
    const int b = blockIdx.x, t = threadIdx.x;
    const int lo = bktBase[b], hi = bktBase[b + 1];

    h[t] = 0;
    __syncthreads();
    for (int i = lo + t; i < hi; i += 256)
        atomicAdd(&h[part[i] & 255], 1);
    __syncthreads();
    int v = h[t];
    sc[t] = v;
    __syncthreads();
    for (int off = 1; off < 256; off <<= 1) {
        int add = (t >= off) ? sc[t - off] : 0;
        __syncthreads();
        sc[t] += add;
        __syncthreads();
    }
    int excl = sc[t] - v;
    cur[t] = lo + excl;
    int node = b * 256 + t;
    if (node < NN) {
        rp[node] = lo + excl;
        cnt[node] = v;
        dinv[node] = rsqrtf((float)v + 1.0f);   // self-loop adds 1
    }
    __syncthreads();
    for (int i = lo + t; i < hi; i += 256) {
        int e = part[i];
        int pos = atomicAdd(&cur[e & 255], 1);
        srcs[pos] = e >> 8;
    }
}

// ---------------------------------------------------------------- GEMM t' = (relu?)(h) @ W * dinv[row], MFMA bf16
// Input: fp32 row-major (layer 0) or bf16 chunk-major [4][NN][32] (layers 1,2).
// Output: bf16 chunk-major tb. W staged to LDS as bf16 B-fragments.
template <bool RELU, bool CHIN>
__global__ __launch_bounds__(256) void k_gemm(const float* __restrict__ hf,
                                              const unsigned short* __restrict__ hb,
                                              const float* __restrict__ W,
                                              const float* __restrict__ dinv,
                                              unsigned short* __restrict__ tb) {
    __shared__ uint4 lw[2048];   // [ct][ks][lane] -> 8 bf16 of B-fragment
    const int tid = threadIdx.x;

    // stage W (fp32 [128][128]) -> LDS bf16 fragments, once per block
    for (int e = tid; e < 2048; e += 256) {
        const int ct = e >> 8, ks = (e >> 6) & 3, l = e & 63;
        const int col = ct * 16 + (l & 15);
        const int kb  = ks * 32 + ((l >> 4) << 3);
        const float* wp = W + (size_t)kb * H + col;
        unsigned int p0 = (unsigned)f2bf(wp[0])     | ((unsigned)f2bf(wp[H])     << 16);
        unsigned int p1 = (unsigned)f2bf(wp[2 * H]) | ((unsigned)f2bf(wp[3 * H]) << 16);
        unsigned int p2 = (unsigned)f2bf(wp[4 * H]) | ((unsigned)f2bf(wp[5 * H]) << 16);
        unsigned int p3 = (unsigned)f2bf(wp[6 * H]) | ((unsigned)f2bf(wp[7 * H]) << 16);
        lw[e] = make_uint4(p0, p1, p2, p3);
    }
    __syncthreads();

    const int wave = tid >> 6, lane = tid & 63;
    const int rowbase = blockIdx.x * 64 + wave * 16;
    const int arow  = rowbase + (lane & 15);
    const int arowc = arow < NN ? arow : NN - 1;   // clamp loads
    const int koff  = (lane >> 4) << 3;

    f32x4 acc[8];
#pragma unroll
    for (int ct = 0; ct < 8; ++ct) acc[ct] = (f32x4){0.f, 0.f, 0.f, 0.f};

#pragma unroll
    for (int ks = 0; ks < 4; ++ks) {
        BF8 a;
        if (CHIN) {
            // bf16 chunk-major: feats ks*32+koff..+7 = one uint4
            a.u = *reinterpret_cast<const uint4*>(
                hb + ((size_t)ks * NN + arowc) * BCW + koff);
            if (RELU) {
                unsigned int m;
                m = ((a.u.x >> 15) & 0x00010001u) * 0xFFFFu; a.u.x &= ~m;
                m = ((a.u.y >> 15) & 0x00010001u) * 0xFFFFu; a.u.y &= ~m;
                m = ((a.u.z >> 15) & 0x00010001u) * 0xFFFFu; a.u.z &= ~m;
                m = ((a.u.w >> 15) & 0x00010001u) * 0xFFFFu; a.u.w &= ~m;
            }
        } else {
            const int kb = ks * 32 + koff;
            const float* base = hf + (size_t)arowc * H + kb;
            float4 h0 = *reinterpret_cast<const float4*>(base);
            float4 h1 = *reinterpret_cast<const float4*>(base + 4);
            if (RELU) {
                h0.x = fmaxf(h0.x, 0.f); h0.y = fmaxf(h0.y, 0.f);
                h0.z = fmaxf(h0.z, 0.f); h0.w = fmaxf(h0.w, 0.f);
                h1.x = fmaxf(h1.x, 0.f); h1.y = fmaxf(h1.y, 0.f);
                h1.z = fmaxf(h1.z, 0.f); h1.w = fmaxf(h1.w, 0.f);
            }
            a.u = make_uint4(
                (unsigned)f2bf(h0.x) | ((unsigned)f2bf(h0.y) << 16),
                (unsigned)f2bf(h0.z) | ((unsigned)f2bf(h0.w) << 16),
                (unsigned)f2bf(h1.x) | ((unsigned)f2bf(h1.y) << 16),
                (unsigned)f2bf(h1.z) | ((unsigned)f2bf(h1.w) << 16));
        }
#pragma unroll
        for (int ct = 0; ct < 8; ++ct) {
            BF8 b;
            b.u = lw[(ct * 4 + ks) * 64 + lane];
            acc[ct] = __builtin_amdgcn_mfma_f32_16x16x32_bf16(a.s, b.s, acc[ct], 0, 0, 0);
        }
    }

    // epilogue: D lane mapping col=lane&15, row=(lane>>4)*4+r
    const int colb = lane & 15;
    const int rrow = rowbase + ((lane >> 4) << 2);
#pragma unroll
    for (int r = 0; r < 4; ++r) {
        const int row = rrow + r;
        if (row < NN) {
            const float d = dinv[row];
#pragma unroll
            for (int ct = 0; ct < 8; ++ct) {
                const int feat = ct * 16 + colb;
                tb[((size_t)(feat >> 5) * NN + row) * BCW + (feat & 31)] =
                    f2bf(acc[ct][r] * d);
            }
        }
    }
}

// ---------------------------------------------------------------- gather (bf16 rows, LDS-staged indices)
// o = bg + dinv[n] * (t'[n] + sum_e t'[src[e]]) ; t' bf16, accum fp32.
// POOL=0: write o as bf16 to aggb (same layout as tb).
// POOL=1 (layer 3): fused mean-pool via shuffle-tree (no LDS-atomic contention).
template <int POOL>
__global__ __launch_bounds__(256) void k_gather(const int* __restrict__ rp,
                                                const int* __restrict__ cnt,
                                                const int* __restrict__ srcs,
                                                const float* __restrict__ dinv,
                                                const float* __restrict__ bg,
                                                const unsigned short* __restrict__ tb,
                                                unsigned short* __restrict__ aggb,
                                                const int* __restrict__ batch,
                                                float* __restrict__ pooled) {
    __shared__ int lsrcs[LSZ];
    const int tid  = threadIdx.x;
    const int wv   = tid >> 6;         // 0..3
    const int lane = tid & 63;
    const int slot = lane >> 2;        // node group 0..15
    const int l4   = lane & 3;         // uint4 index within 64B row
    const int c    = blockIdx.x & 3;   // bf16 chunk (XCD affinity)
    const int nb   = blockIdx.x >> 2;  // node block (64 nodes)
    const int n0   = nb * 64;
    const int n    = n0 + wv * 16 + slot;

    const int eLo = rp[n0];
    int nLast = n0 + 63; if (nLast >= NN) nLast = NN - 1;
    const int eHi = rp[nLast] + cnt[nLast];
    const bool staged = (eHi - eLo) <= LSZ;   // block-uniform

    if (staged) {
        for (int i = eLo + tid; i < eHi; i += 256)
            lsrcs[i - eLo] = srcs[i];
    }

    __shared__ float psum[4][32];   // POOL accumulator (unused if POOL==0)
    int g0 = 0, gspan = 0;
    if (POOL) {
        if (tid < 128) psum[tid >> 5][tid & 31] = 0.f;
        g0 = batch[n0];
        gspan = batch[nLast] - g0;   // block-uniform
    }
    __syncthreads();

    if (n >= NN) return;

    const uint4* __restrict__ tb4 =
        reinterpret_cast<const uint4*>(tb) + (size_t)c * NN * 4;
    const float4 bg0 = *reinterpret_cast<const float4*>(bg + c * BCW + l4 * 8);
    const float4 bg1 = *reinterpret_cast<const float4*>(bg + c * BCW + l4 * 8 + 4);

    const int i0  = rp[n];
    const int end = i0 + cnt[n];
    float4 p = make_float4(0.f, 0.f, 0.f, 0.f);
    float4 q = make_float4(0.f, 0.f, 0.f, 0.f);

#define ACC8(v)                                                        \
    do {                                                               \
        p.x += __uint_as_float((v).x << 16);                           \
        p.y += __uint_as_float((v).x & 0xFFFF0000u);                   \
        p.z += __uint_as_float((v).y << 16);                           \
        p.w += __uint_as_float((v).y & 0xFFFF0000u);                   \
        q.x += __uint_as_float((v).z << 16);                           \
        q.y += __uint_as_float((v).z & 0xFFFF0000u);                   \
        q.z += __uint_as_float((v).w << 16);                           \
        q.w += __uint_as_float((v).w & 0xFFFF0000u);                   \
    } while (0)

    if (staged) {
        int i = i0;
        for (; i + 7 < end; i += 8) {
            int s0 = lsrcs[i     - eLo], s1 = lsrcs[i + 1 - eLo];
            int s2 = lsrcs[i + 2 - eLo], s3 = lsrcs[i + 3 - eLo];
            int s4 = lsrcs[i + 4 - eLo], s5 = lsrcs[i + 5 - eLo];
            int s6 = lsrcs[i + 6 - eLo], s7 = lsrcs[i + 7 - eLo];
            uint4 v0 = tb4[(size_t)s0 * 4 + l4];
            uint4 v1 = tb4[(size_t)s1 * 4 + l4];
            uint4 v2 = tb4[(size_t)s2 * 4 + l4];
            uint4 v3 = tb4[(size_t)s3 * 4 + l4];
            uint4 v4 = tb4[(size_t)s4 * 4 + l4];
            uint4 v5 = tb4[(size_t)s5 * 4 + l4];
            uint4 v6 = tb4[(size_t)s6 * 4 + l4];
            uint4 v7 = tb4[(size_t)s7 * 4 + l4];
            ACC8(v0); ACC8(v1); ACC8(v2); ACC8(v3);
            ACC8(v4); ACC8(v5); ACC8(v6); ACC8(v7);
        }
        for (; i < end; ++i) {
            uint4 v = tb4[(size_t)lsrcs[i - eLo] * 4 + l4];
            ACC8(v);
        }
    } else {
        int i = i0;
        for (; i + 3 < end; i += 4) {
            int s0 = srcs[i], s1 = srcs[i + 1], s2 = srcs[i + 2], s3 = srcs[i + 3];
            uint4 v0 = tb4[(size_t)s0 * 4 + l4];
            uint4 v1 = tb4[(size_t)s1 * 4 + l4];
            uint4 v2 = tb4[(size_t)s2 * 4 + l4];
            uint4 v3 = tb4[(size_t)s3 * 4 + l4];
            ACC8(v0); ACC8(v1); ACC8(v2); ACC8(v3);
        }
        for (; i < end; ++i) {
            uint4 v = tb4[(size_t)srcs[i] * 4 + l4];
            ACC8(v);
        }
    }

    uint4 sv = tb4[(size_t)n * 4 + l4];   // self-loop term
    ACC8(sv);
#undef ACC8

    const float d = dinv[n];
    float4 o0, o1;
    o0.x = fmaf(p.x, d, bg0.x); o0.y = fmaf(p.y, d, bg0.y);
    o0.z = fmaf(p.z, d, bg0.z); o0.w = fmaf(p.w, d, bg0.w);
    o1.x = fmaf(q.x, d, bg1.x); o1.y = fmaf(q.y, d, bg1.y);
    o1.z = fmaf(q.z, d, bg1.z); o1.w = fmaf(q.w, d, bg1.w);

    if (POOL == 0) {
        uint4 u;
        u.x = (unsigned)f2bf(o0.x) | ((unsigned)f2bf(o0.y) << 16);
        u.y = (unsigned)f2bf(o0.z) | ((unsigned)f2bf(o0.w) << 16);
        u.z = (unsigned)f2bf(o1.x) | ((unsigned)f2bf(o1.y) << 16);
        u.w = (unsigned)f2bf(o1.z) | ((unsigned)f2bf(o1.w) << 16);
        *reinterpret_cast<uint4*>(aggb + ((size_t)c * NN + n) * BCW + l4 * 8) = u;
    } else {
        // relu + mean-pool
        o0.x = fmaxf(o0.x, 0.f); o0.y = fmaxf(o0.y, 0.f);
        o0.z = fmaxf(o0.z, 0.f); o0.w = fmaxf(o0.w, 0.f);
        o1.x = fmaxf(o1.x, 0.f); o1.y = fmaxf(o1.y, 0.f);
        o1.z = fmaxf(o1.z, 0.f); o1.w = fmaxf(o1.w, 0.f);
        if (gspan > 3) {
            // >4 graphs in a 64-node block: ~impossible; direct global atomics
            float* dst = pooled + (size_t)batch[n] * H + c * BCW + l4 * 8;
            atomicAdd(dst + 0, o0.x); atomicAdd(dst + 1, o0.y);
            atomicAdd(dst + 2, o0.z); atomicAdd(dst + 3, o0.w);
            atomicAdd(dst + 4, o1.x); atomicAdd(dst + 5, o1.y);
            atomicAdd(dst + 6, o1.z); atomicAdd(dst + 7, o1.w);
        } else if (gspan == 0) {
            // single-graph block (common): shuffle-tree over slot bits (2..5)
#pragma unroll
            for (int m = 4; m <= 32; m <<= 1) {
                o0.x += __shfl_xor(o0.x, m); o0.y += __shfl_xor(o0.y, m);
                o0.z += __shfl_xor(o0.z, m); o0.w += __shfl_xor(o0.w, m);
                o1.x += __shfl_xor(o1.x, m); o1.y += __shfl_xor(o1.y, m);
                o1.z += __shfl_xor(o1.z, m); o1.w += __shfl_xor(o1.w, m);
            }
            if (slot == 0) {      // lane = l4 (0..3): wave-sum for feats l4*8..+7
                float* ps = &psum[wv][l4 * 8];
                ps[0] = o0.x; ps[1] = o0.y; ps[2] = o0.z; ps[3] = o0.w;
                ps[4] = o1.x; ps[5] = o1.y; ps[6] = o1.z; ps[7] = o1.w;
            }
            __syncthreads();
            if (tid < 32) {
                float v = psum[0][tid] + psum[1][tid] + psum[2][tid] + psum[3][tid];
                atomicAdd(&pooled[(size_t)g0 * H + c * BCW + tid], v);
            }
        } else {
            // graph-boundary block (~8%): LDS atomics (contention amortized)
            const int gi = batch[n] - g0;
            float* ps = &psum[gi][l4 * 8];
            atomicAdd(ps + 0, o0.x); atomicAdd(ps + 1, o0.y);
            atomicAdd(ps + 2, o0.z); atomicAdd(ps + 3, o0.w);
            atomicAdd(ps + 4, o1.x); atomicAdd(ps + 5, o1.y);
            atomicAdd(ps + 6, o1.z); atomicAdd(ps + 7, o1.w);
            __syncthreads();
            if (tid < 128) {
                int gi2 = tid >> 5, f = tid & 31;
                float v = psum[gi2][f];
                if (v != 0.f)
                    atomicAdd(&pooled[(size_t)(g0 + gi2) * H + c * BCW + f], v);
            }
        }
    }
}

// ---------------------------------------------------------------- helpers
__device__ __forceinline__ int lower_bound_dev(const int* __restrict__ b, int v) {
    int lo = 0, hi = NN;
    while (lo < hi) {
        int m = (lo + hi) >> 1;
        if (b[m] < v) lo = m + 1; else hi = m;
    }
    return lo;
}

// ---------------------------------------------------------------- LSTM (single step, h0=c0=0) + output head, fused
__global__ __launch_bounds__(256) void k_lstm(const float* __restrict__ pooled,
                                              const int* __restrict__ batch,
                                              const float* __restrict__ W_ih,
                                              const float* __restrict__ b_ih,
                                              const float* __restrict__ b_hh,
                                              const float* __restrict__ W_out,
                                              const float* __restrict__ b_out,
                                              float* __restrict__ out) {
    __shared__ __align__(16) float p[H];
    __shared__ __align__(16) float hn[LH];
    int g = blockIdx.x, t = threadIdx.x;
    if (t < H) {
        int s = lower_bound_dev(batch, g);
        int e = lower_bound_dev(batch, g + 1);
        p[t] = pooled[g * H + t] / fmaxf((float)(e - s), 1.f);
    }
    __syncthreads();

    // gate rows (torch order i,f,g,o): f unused (c0=0)
    float si = b_ih[t] + b_hh[t];
    float sg = b_ih[2 * LH + t] + b_hh[2 * LH + t];
    float so = b_ih[3 * LH + t] + b_hh[3 * LH + t];
    const float* wi = W_ih + (size_t)t * H;
    const float* wg = W_ih + (size_t)(2 * LH + t) * H;
    const float* wo = W_ih + (size_t)(3 * LH + t) * H;
    for (int k = 0; k < H; k += 4) {
        float4 pv = *reinterpret_cast<const float4*>(&p[k]);
        float4 a = *reinterpret_cast<const float4*>(wi + k);
        si += pv.x * a.x + pv.y * a.y + pv.z * a.z + pv.w * a.w;
        float4 b = *reinterpret_cast<const float4*>(wg + k);
        sg += pv.x * b.x + pv.y * b.y + pv.z * b.z + pv.w * b.w;
        float4 c = *reinterpret_cast<const float4*>(wo + k);
        so += pv.x * c.x + pv.y * c.y + pv.z * c.z + pv.w * c.w;
    }
    float ig = 1.f / (1.f + expf(-si));
    float cc = ig * tanhf(sg);
    float og = 1.f / (1.f + expf(-so));
    hn[t] = og * tanhf(cc);
    __syncthreads();

    if (t < OD) {
        float acc = b_out[t];
        const float* wr = W_out + (size_t)t * LH;
        for (int k = 0; k < LH; k += 4) {
            float4 hv = *reinterpret_cast<const float4*>(&hn[k]);
            float4 wv = *reinterpret_cast<const float4*>(wr + k);
            acc += hv.x * wv.x + hv.y * wv.y + hv.z * wv.z + hv.w * wv.w;
        }
        out[g * OD + t] = acc;
    }
}

// ----------------------------------------------------------------
extern "C" void kernel_launch(void* const* d_in, const int* in_sizes, int n_in,
                              void* d_out, int out_size, void* d_ws, size_t ws_size,
                              hipStream_t stream) {
    const float* x     = (const float*)d_in[0];
    const int*   ei    = (const int*)d_in[1];   // [2][NE]: rows then cols
    const int*   batch = (const int*)d_in[2];
    const float* Wg    = (const float*)d_in[3]; // [3][128][128]
    const float* bg    = (const float*)d_in[4]; // [3][128]
    const float* W_ih  = (const float*)d_in[5]; // [1024][128]
    const float* b_ih  = (const float*)d_in[7];
    const float* b_hh  = (const float*)d_in[8];
    const float* W_out = (const float*)d_in[9]; // [32][256]
    const float* b_out = (const float*)d_in[10];
    float* out = (float*)d_out;

    // workspace layout (~39 MB)
    unsigned short* tb   = (unsigned short*)d_ws;     // NN*H bf16 (12.8 MB)
    unsigned short* aggb = tb + (size_t)NN * H;       // NN*H bf16 (12.8 MB)
    int*   part      = (int*)(aggb + (size_t)NN * H); // NE ints (packed)
    float* dinv      = (float*)(part + NE);           // NN
    float* pooled    = dinv + NN;                     // NG*H
    int*   cnt       = (int*)(pooled + NG * H);       // NN
    int*   rp        = cnt + NN;                      // NN
    int*   srcs      = rp + NN;                       // NE
    int*   bktCnt    = srcs + NE;                     // NBKT
    int*   bktBase   = bktCnt + NBKT;                 // NBKT+1
    int*   bktCursor = bktBase + NBKT + 1;            // NBKT

    hipMemsetAsync(bktCnt, 0, NBKT * sizeof(int), stream);
    hipMemsetAsync(pooled, 0, NG * H * sizeof(float), stream);

    // CSR build (by destination) — bucketed counting sort
    k_bhist<<<256, 256, 0, stream>>>(ei + NE, bktCnt);
    k_bscan<<<1, 256, 0, stream>>>(bktCnt, bktBase, bktCursor);
    k_part <<<NPARTB, 256, 0, stream>>>(ei, bktCursor, part);
    k_bfill<<<NBKT, 256, 0, stream>>>(bktBase, part, rp, cnt, dinv, srcs);

    const int gemmBlocks = (NN + 63) / 64;
    const int gathBlocks = ((NN + 63) / 64) * BCH;   // 782 * 4 = 3128

    // layer 0: x (fp32 row-major) -> tb -> aggb
    k_gemm<false, false><<<gemmBlocks, 256, 0, stream>>>(x, nullptr, Wg, dinv, tb);
    k_gather<0><<<gathBlocks, 256, 0, stream>>>(rp, cnt, srcs, dinv, bg, tb, aggb, batch, pooled);
    // layer 1: relu(aggb) -> tb -> aggb
    k_gemm<true, true><<<gemmBlocks, 256, 0, stream>>>(nullptr, aggb, Wg + H * H, dinv, tb);
    k_gather<0><<<gathBlocks, 256, 0, stream>>>(rp, cnt, srcs, dinv, bg + H, tb, aggb, batch, pooled);
    // layer 2: relu(aggb) -> tb -> pooled (pool fused)
    k_gemm<true, true><<<gemmBlocks, 256, 0, stream>>>(nullptr, aggb, Wg + 2 * H * H, dinv, tb);
    k_gather<1><<<gathBlocks, 256, 0, stream>>>(rp, cnt, srcs, dinv, bg + 2 * H, tb, nullptr, batch, pooled);

    k_lstm<<<NG, 256, 0, stream>>>(pooled, batch, W_ih, b_ih, b_hh, W_out, b_out, out);
}